// Round 6
// baseline (227.625 us; speedup 1.0000x reference)
//
#include <hip/hip_runtime.h>

#define N_NODES 50000
#define E_EDGES 800000
#define IN_DIM  128
#define OUT_DIM 64
#define NEG_SLOPE 0.01f
#define SCAN_NB  ((N_NODES + 255) / 256)   // 196
#define LDAP 136                            // padded bf16 row stride

#define BUCKETS 196                         // ceil(N/256): bucket = dst>>8
#define NBLK    196                         // sort blocks
#define CHUNK   4096                        // edges per sort block
#define TOTW    (BUCKETS * NBLK)            // 38416
#define P2CAP   6144

typedef __attribute__((ext_vector_type(8))) short bf16x8;
typedef __attribute__((ext_vector_type(4))) float f32x4;

__device__ __forceinline__ ushort f2bf(float x) {
    unsigned u = __float_as_uint(x);
    return (ushort)((u + 0x7FFFu + ((u >> 16) & 1u)) >> 16);
}
__device__ __forceinline__ float bf2f(ushort u) {
    return __uint_as_float(((unsigned)u) << 16);
}
__device__ __forceinline__ unsigned edge_hash(unsigned pay) {
    return pay * 2654435761u + 0x9e3779b9u;
}

// flag[0]=probe mapping (0/1/4), flag[1]=verify mismatches, flag[2]=sort-check mismatches
__global__ void probe_kernel(int* flag) {
    int lane = threadIdx.x & 63;
    bf16x8 af = {0,0,0,0,0,0,0,0};
    bf16x8 bf = {0,0,0,0,0,0,0,0};
    if (lane < 16) {
        af[0] = (short)f2bf((float)(1 + lane));
        bf[0] = (short)f2bf((float)((1 + lane) * (1 + lane)));
    }
    f32x4 acc = {0.f, 0.f, 0.f, 0.f};
    acc = __builtin_amdgcn_mfma_f32_16x16x32_bf16(af, bf, acc, 0, 0, 0);
    int lr = lane & 15, lq = lane >> 4;
    bool ok0 = true, ok1 = true;
    #pragma unroll
    for (int r = 0; r < 4; ++r) {
        float e0 = (float)((1 + lq * 4 + r) * (1 + lr) * (1 + lr));
        float e1 = (float)((1 + lr) * (1 + lq * 4 + r) * (1 + lq * 4 + r));
        ok0 = ok0 && (acc[r] == e0);
        ok1 = ok1 && (acc[r] == e1);
    }
    int f = __all(ok0 ? 1 : 0) ? 0 : (__all(ok1 ? 1 : 0) ? 1 : 4);
    if (threadIdx.x == 0) { flag[0] = f; flag[1] = 0; flag[2] = 0; }
}

// ============ MFMA gemm: z/zr only (round-4 exact) ============
__global__ __launch_bounds__(256) void node_gemm_mfma(
    const float* __restrict__ h, const float* __restrict__ Wf,
    const float* __restrict__ Wfr, const int* __restrict__ flag,
    ushort* __restrict__ z, ushort* __restrict__ zr)
{
    const int flagv = flag[0];
    if (flagv >= 2) return;

    __shared__ ushort hs [64 * LDAP];
    __shared__ ushort wfs[64 * LDAP];
    __shared__ ushort wrs[64 * LDAP];

    const int t = threadIdx.x;
    const int nb0 = blockIdx.x * 64;

    #pragma unroll
    for (int i = 0; i < 8; ++i) {
        int elem = i * 1024 + t * 4;
        int row = elem >> 7, col = elem & 127;
        int hn = nb0 + row; if (hn >= N_NODES) hn = N_NODES - 1;
        float4 hv = *(const float4*)&h  [(size_t)hn  * IN_DIM + col];
        float4 fv = *(const float4*)&Wf [(size_t)row * IN_DIM + col];
        float4 rv = *(const float4*)&Wfr[(size_t)row * IN_DIM + col];
        ushort4 hu = { f2bf(hv.x), f2bf(hv.y), f2bf(hv.z), f2bf(hv.w) };
        ushort4 fu = { f2bf(fv.x), f2bf(fv.y), f2bf(fv.z), f2bf(fv.w) };
        ushort4 ru = { f2bf(rv.x), f2bf(rv.y), f2bf(rv.z), f2bf(rv.w) };
        *(ushort4*)&hs [row * LDAP + col] = hu;
        *(ushort4*)&wfs[row * LDAP + col] = fu;
        *(ushort4*)&wrs[row * LDAP + col] = ru;
    }
    __syncthreads();

    const int w    = t >> 6;
    const int lane = t & 63;
    const int lr   = lane & 15;
    const int lq   = lane >> 4;

    f32x4 accf[4], accr[4];
    #pragma unroll
    for (int cb = 0; cb < 4; ++cb) {
        accf[cb] = (f32x4){0.f, 0.f, 0.f, 0.f};
        accr[cb] = (f32x4){0.f, 0.f, 0.f, 0.f};
    }

    #pragma unroll
    for (int kc = 0; kc < 4; ++kc) {
        const int koff = kc * 32 + lq * 8;
        bf16x8 af = *(bf16x8*)&hs[(w * 16 + lr) * LDAP + koff];
        #pragma unroll
        for (int cb = 0; cb < 4; ++cb) {
            bf16x8 bfr = *(bf16x8*)&wfs[(cb * 16 + lr) * LDAP + koff];
            bf16x8 brr = *(bf16x8*)&wrs[(cb * 16 + lr) * LDAP + koff];
            accf[cb] = __builtin_amdgcn_mfma_f32_16x16x32_bf16(af, bfr, accf[cb], 0, 0, 0);
            accr[cb] = __builtin_amdgcn_mfma_f32_16x16x32_bf16(af, brr, accr[cb], 0, 0, 0);
        }
    }

    #pragma unroll
    for (int reg = 0; reg < 4; ++reg) {
        const int aIdx = (flagv == 0) ? (lq * 4 + reg) : lr;
        const int bIdx = (flagv == 0) ? lr : (lq * 4 + reg);
        const int node = nb0 + w * 16 + aIdx;
        if (node < N_NODES) {
            #pragma unroll
            for (int cb = 0; cb < 4; ++cb) {
                z [(size_t)node * OUT_DIM + cb * 16 + bIdx] = f2bf(accf[cb][reg]);
                zr[(size_t)node * OUT_DIM + cb * 16 + bIdx] = f2bf(accr[cb][reg]);
            }
        }
    }
}

// ============ verify 8192 sampled z/zr vs fp32 dots ============
__global__ __launch_bounds__(256) void verify_kernel(
    const float* __restrict__ h, const float* __restrict__ Wf,
    const float* __restrict__ Wfr, const ushort* __restrict__ z,
    const ushort* __restrict__ zr, int* __restrict__ flag)
{
    if (flag[0] >= 2) return;
    int i = blockIdx.x * 256 + threadIdx.x;
    unsigned u = (unsigned)i * 2654435761u;
    int n = (int)(u % (unsigned)N_NODES);
    int o = (int)((u >> 17) & 63);
    const ushort* zz = (i & 1) ? zr : z;
    const float*  W  = (i & 1) ? Wfr : Wf;
    float s = 0.f;
    #pragma unroll 4
    for (int k = 0; k < IN_DIM; k += 4) {
        float4 hv = *(const float4*)&h[(size_t)n * IN_DIM + k];
        float4 wv = *(const float4*)&W[(size_t)o * IN_DIM + k];
        s = fmaf(hv.x, wv.x, s); s = fmaf(hv.y, wv.y, s);
        s = fmaf(hv.z, wv.z, s); s = fmaf(hv.w, wv.w, s);
    }
    float zv = bf2f(zz[(size_t)n * OUT_DIM + o]);
    if (fabsf(s - zv) > 0.125f + 0.02f * fabsf(s)) atomicAdd(&flag[1], 1);
}

// ============ VALU fallback gemm (round-2/4 proven) ============
__global__ __launch_bounds__(256) void node_gemm_valu(
    const float* __restrict__ h, const float* __restrict__ Wf,
    const float* __restrict__ Wfr, const int* __restrict__ flag,
    ushort* __restrict__ z, ushort* __restrict__ zr)
{
    if (flag[0] < 2 && flag[1] == 0) return;

    __shared__ float hs [64][33];
    __shared__ float wfs[64][33];
    __shared__ float wrs[64][33];

    const int tid = threadIdx.x;
    const int og = tid & 15;
    const int ng = tid >> 4;
    const int nb0 = blockIdx.x * 64;

    float accf[4][4] = {{0.f}};
    float accr[4][4] = {{0.f}};

    for (int kb = 0; kb < IN_DIM; kb += 32) {
        __syncthreads();
        const int j = tid & 7;
        const int r0 = tid >> 3;
        for (int rr = r0; rr < 64; rr += 32) {
            int hn = nb0 + rr; if (hn >= N_NODES) hn = N_NODES - 1;
            float4 hv = *(const float4*)&h  [(size_t)hn * IN_DIM + kb + j*4];
            float4 fv = *(const float4*)&Wf [(size_t)rr * IN_DIM + kb + j*4];
            float4 rv = *(const float4*)&Wfr[(size_t)rr * IN_DIM + kb + j*4];
            hs [rr][j*4+0] = hv.x; hs [rr][j*4+1] = hv.y; hs [rr][j*4+2] = hv.z; hs [rr][j*4+3] = hv.w;
            wfs[rr][j*4+0] = fv.x; wfs[rr][j*4+1] = fv.y; wfs[rr][j*4+2] = fv.z; wfs[rr][j*4+3] = fv.w;
            wrs[rr][j*4+0] = rv.x; wrs[rr][j*4+1] = rv.y; wrs[rr][j*4+2] = rv.z; wrs[rr][j*4+3] = rv.w;
        }
        __syncthreads();

        #pragma unroll 8
        for (int k = 0; k < 32; ++k) {
            float hv[4], wfv[4], wrv[4];
            #pragma unroll
            for (int i = 0; i < 4; ++i) hv[i] = hs[ng*4+i][k];
            #pragma unroll
            for (int jj = 0; jj < 4; ++jj) { wfv[jj] = wfs[og*4+jj][k]; wrv[jj] = wrs[og*4+jj][k]; }
            #pragma unroll
            for (int i = 0; i < 4; ++i)
                #pragma unroll
                for (int jj = 0; jj < 4; ++jj) {
                    accf[i][jj] = fmaf(hv[i], wfv[jj], accf[i][jj]);
                    accr[i][jj] = fmaf(hv[i], wrv[jj], accr[i][jj]);
                }
        }
    }

    #pragma unroll
    for (int i = 0; i < 4; ++i) {
        const int n = nb0 + ng*4 + i;
        if (n < N_NODES) {
            #pragma unroll
            for (int jj = 0; jj < 4; ++jj) {
                z [(size_t)n*OUT_DIM + og*4 + jj] = f2bf(accf[i][jj]);
                zr[(size_t)n*OUT_DIM + og*4 + jj] = f2bf(accr[i][jj]);
            }
        }
    }
}

// ============ a4 from global z/zr (layout-independent, round-4 proven) ============
__global__ __launch_bounds__(256) void a4_kernel(
    const ushort* __restrict__ z, const ushort* __restrict__ zr,
    const float* __restrict__ Wa, float4* __restrict__ a4)
{
    int gid = blockIdx.x * 256 + threadIdx.x;
    int node = gid >> 4;
    int lr = threadIdx.x & 15;
    if (node >= N_NODES) return;
    ushort4 zv = *(const ushort4*)&z [(size_t)node * OUT_DIM + lr * 4];
    ushort4 rv = *(const ushort4*)&zr[(size_t)node * OUT_DIM + lr * 4];
    float4 ws4 = *(const float4*)&Wa[lr * 4];
    float4 wd4 = *(const float4*)&Wa[64 + lr * 4];
    float pSf = bf2f(zv.x)*ws4.x + bf2f(zv.y)*ws4.y + bf2f(zv.z)*ws4.z + bf2f(zv.w)*ws4.w;
    float pDf = bf2f(zv.x)*wd4.x + bf2f(zv.y)*wd4.y + bf2f(zv.z)*wd4.z + bf2f(zv.w)*wd4.w;
    float pSr = bf2f(rv.x)*ws4.x + bf2f(rv.y)*ws4.y + bf2f(rv.z)*ws4.z + bf2f(rv.w)*ws4.w;
    float pDr = bf2f(rv.x)*wd4.x + bf2f(rv.y)*wd4.y + bf2f(rv.z)*wd4.z + bf2f(rv.w)*wd4.w;
    #pragma unroll
    for (int mm = 1; mm < 16; mm <<= 1) {
        pSf += __shfl_xor(pSf, mm, 64);
        pDf += __shfl_xor(pDf, mm, 64);
        pSr += __shfl_xor(pSr, mm, 64);
        pDr += __shfl_xor(pDr, mm, 64);
    }
    if (lr == 0) a4[node] = make_float4(pSf, pDf, pSr, pDr);
}

// ============ new sort chain (under test; checksum-validated below) ============
__global__ __launch_bounds__(256) void sort_hist(
    const int* __restrict__ dst, int* __restrict__ counts)
{
    __shared__ int bh[BUCKETS];
    const int b = blockIdx.x;
    for (int i = threadIdx.x; i < BUCKETS; i += 256) bh[i] = 0;
    __syncthreads();
    const int base = b * CHUNK;
    const int end = (base + CHUNK < E_EDGES) ? base + CHUNK : E_EDGES;
    for (int i = base + threadIdx.x; i < end; i += 256)
        atomicAdd(&bh[dst[i] >> 8], 1);
    __syncthreads();
    for (int i = threadIdx.x; i < BUCKETS; i += 256)
        counts[i * NBLK + b] = bh[i];
}

__global__ __launch_bounds__(1024) void sort_scan(
    const int* __restrict__ counts, int* __restrict__ scan)
{
    __shared__ int part[1024];
    const int CH = (TOTW + 1023) / 1024;
    const int t = threadIdx.x;
    const int b0 = t * CH;
    int s = 0;
    for (int i = 0; i < CH; ++i) {
        int idx = b0 + i;
        if (idx < TOTW) s += counts[idx];
    }
    part[t] = s; __syncthreads();
    for (int off = 1; off < 1024; off <<= 1) {
        int v = (t >= off) ? part[t - off] : 0;
        __syncthreads();
        part[t] += v;
        __syncthreads();
    }
    int run = (t > 0) ? part[t - 1] : 0;
    for (int i = 0; i < CH; ++i) {
        int idx = b0 + i;
        if (idx < TOTW) { int c = counts[idx]; scan[idx] = run; run += c; }
    }
    if (t == 1023) scan[TOTW] = part[1023];
}

__global__ __launch_bounds__(256) void sort_scatter1(
    const int* __restrict__ src, const int* __restrict__ dst,
    const float2* __restrict__ dir, const int* __restrict__ scan,
    int2* __restrict__ tmp)
{
    __shared__ int2 recs[CHUNK];
    __shared__ int bh[BUCKETS];
    __shared__ int sc[256];
    __shared__ int cur[BUCKETS];

    const int b = blockIdx.x;
    const int t = threadIdx.x;
    const int base = b * CHUNK;
    const int end = (base + CHUNK < E_EDGES) ? base + CHUNK : E_EDGES;
    const int cnt = end - base;

    for (int i = t; i < BUCKETS; i += 256) bh[i] = 0;
    __syncthreads();

    for (int i = t; i < cnt; i += 256) {
        int e = base + i;
        int d = dst[e];
        float2 dd = dir[e];
        int pay = src[e] | ((dd.y != 0.f) ? 0x80000000 : 0);
        recs[i] = make_int2(pay, d);
        atomicAdd(&bh[d >> 8], 1);
    }
    __syncthreads();

    sc[t] = (t < BUCKETS) ? bh[t] : 0;
    __syncthreads();
    for (int off = 1; off < 256; off <<= 1) {
        int v = (t >= off) ? sc[t - off] : 0;
        __syncthreads();
        sc[t] += v;
        __syncthreads();
    }
    if (t < BUCKETS) cur[t] = (t > 0) ? sc[t - 1] : 0;
    __syncthreads();

    for (int i = t; i < cnt; i += 256) {
        int2 r = recs[i];
        int bkt = r.y >> 8;
        int loc = atomicAdd(&cur[bkt], 1);
        int lbase = (bkt > 0) ? sc[bkt - 1] : 0;
        tmp[scan[bkt * NBLK + b] + (loc - lbase)] = r;
    }
}

__global__ __launch_bounds__(256) void sort_pass2(
    const int* __restrict__ scan, const int2* __restrict__ tmp,
    int* __restrict__ csr, int* __restrict__ start)
{
    __shared__ int nh[256];
    __shared__ int nex[256];
    __shared__ int ncur[256];
    __shared__ int2 recs[P2CAP];

    const int j = blockIdx.x;
    const int t = threadIdx.x;
    const int gbeg = scan[j * NBLK];
    const int gend = scan[(j + 1) * NBLK];
    const int cnt = gend - gbeg;
    const bool fits = (cnt <= P2CAP);

    nh[t] = 0;
    __syncthreads();

    for (int i = t; i < cnt; i += 256) {
        int2 r = tmp[gbeg + i];
        if (fits) recs[i] = r;
        atomicAdd(&nh[r.y & 255], 1);
    }
    __syncthreads();

    nex[t] = nh[t];
    __syncthreads();
    for (int off = 1; off < 256; off <<= 1) {
        int v = (t >= off) ? nex[t - off] : 0;
        __syncthreads();
        nex[t] += v;
        __syncthreads();
    }
    int excl = (t > 0) ? nex[t - 1] : 0;
    ncur[t] = excl;
    const int node = j * 256 + t;
    if (node < N_NODES) start[node] = gbeg + excl;
    if (j == BUCKETS - 1 && t == 0) start[N_NODES] = E_EDGES;
    __syncthreads();

    for (int i = t; i < cnt; i += 256) {
        int2 r = fits ? recs[i] : tmp[gbeg + i];
        int lid = r.y & 255;
        int loc = atomicAdd(&ncur[lid], 1);
        csr[gbeg + loc] = r.x;
    }
}

// ============ CSR checksum validation ============
__global__ __launch_bounds__(256) void chk_edges(
    const int* __restrict__ src, const int* __restrict__ dst,
    const float2* __restrict__ dir, unsigned* __restrict__ csA)
{
    int e = blockIdx.x * 256 + threadIdx.x;
    if (e >= E_EDGES) return;
    unsigned pay = (unsigned)src[e] | ((dir[e].y != 0.f) ? 0x80000000u : 0u);
    atomicAdd(&csA[dst[e]], edge_hash(pay));
}

__global__ __launch_bounds__(256) void chk_csr(
    const int* __restrict__ start, const int* __restrict__ csr,
    const unsigned* __restrict__ csA, int* __restrict__ flag)
{
    int n = blockIdx.x * 256 + threadIdx.x;
    if (n >= N_NODES) return;
    int s = start[n], e1 = start[n + 1];
    if (s < 0 || e1 < s || e1 > E_EDGES || (n == 0 && s != 0)) {
        atomicAdd(&flag[2], 1); return;
    }
    unsigned acc = 0;
    for (int k = s; k < e1; ++k) acc += edge_hash((unsigned)csr[k]);
    if (acc != csA[n]) atomicAdd(&flag[2], 1);
}

// ============ guarded fallback: round-4-proven CSR build ============
__global__ __launch_bounds__(256) void fb_hist(
    const int* __restrict__ dst, int* __restrict__ deg, const int* __restrict__ flag)
{
    if (flag[2] == 0) return;
    int e = blockIdx.x * 256 + threadIdx.x;
    if (e < E_EDGES) atomicAdd(&deg[dst[e]], 1);
}

__global__ __launch_bounds__(256) void fb_scan1(
    const int* __restrict__ deg, int* __restrict__ excl, int* __restrict__ bsum,
    const int* __restrict__ flag)
{
    if (flag[2] == 0) return;
    __shared__ int tmp[256];
    int tid = threadIdx.x;
    int i = blockIdx.x * 256 + tid;
    int v = (i < N_NODES) ? deg[i] : 0;
    tmp[tid] = v; __syncthreads();
    #pragma unroll
    for (int off = 1; off < 256; off <<= 1) {
        int t = (tid >= off) ? tmp[tid - off] : 0;
        __syncthreads();
        tmp[tid] += t;
        __syncthreads();
    }
    if (i < N_NODES) excl[i] = tmp[tid] - v;
    if (tid == 255) bsum[blockIdx.x] = tmp[tid];
}

__global__ __launch_bounds__(256) void fb_scan2(
    const int* __restrict__ bsum, int* __restrict__ boff, const int* __restrict__ flag)
{
    if (flag[2] == 0) return;
    __shared__ int tmp[256];
    int tid = threadIdx.x;
    int v = (tid < SCAN_NB) ? bsum[tid] : 0;
    tmp[tid] = v; __syncthreads();
    #pragma unroll
    for (int off = 1; off < 256; off <<= 1) {
        int t = (tid >= off) ? tmp[tid - off] : 0;
        __syncthreads();
        tmp[tid] += t;
        __syncthreads();
    }
    if (tid < SCAN_NB) boff[tid] = tmp[tid] - v;
}

__global__ __launch_bounds__(256) void fb_scan3(
    int* __restrict__ excl, const int* __restrict__ boff, const int* __restrict__ flag)
{
    if (flag[2] == 0) return;
    int i = blockIdx.x * 256 + threadIdx.x;
    if (i < N_NODES) excl[i] += boff[blockIdx.x];
    if (i == 0) excl[N_NODES] = E_EDGES;   // sentinel
}

__global__ __launch_bounds__(256) void fb_scatter(
    const int* __restrict__ src, const int* __restrict__ dst,
    const float2* __restrict__ dir, const int* __restrict__ start,
    int* __restrict__ cursor, int* __restrict__ csr, const int* __restrict__ flag)
{
    if (flag[2] == 0) return;
    int e = blockIdx.x * 256 + threadIdx.x;
    if (e >= E_EDGES) return;
    int dd = dst[e];
    int pos = atomicAdd(&cursor[dd], 1);
    float2 d = dir[e];
    int packed = src[e] | ((d.y != 0.f) ? 0x80000000 : 0);
    csr[start[dd] + pos] = packed;
}

// ============ fused softmax+aggregate: round-4 proven 64-lane ============
__global__ __launch_bounds__(256) void node_aggregate(
    const int* __restrict__ start, const int* __restrict__ csr,
    const float4* __restrict__ a4, const ushort* __restrict__ z,
    const ushort* __restrict__ zr, float* __restrict__ out)
{
    int gid = blockIdx.x * 256 + threadIdx.x;
    int node = gid >> 6;
    int lane = threadIdx.x & 63;
    if (node >= N_NODES) return;

    const int s0 = start[node];
    const int s1 = start[node + 1];
    const float4 an = a4[node];

    float m = -__builtin_inff();
    float ssum = 0.f;
    float acc = 0.f;

    for (int base = s0; base < s1; base += 64) {
        int k = base + lane;
        int p = 0;
        float em = -__builtin_inff();
        if (k < s1) {
            p = csr[k];
            int sd = p & 0x7FFFFFFF;
            float4 a = a4[sd];
            float tl = (p < 0) ? (a.z + an.w) : (a.x + an.y);
            em = (tl > 0.f) ? tl : NEG_SLOPE * tl;
        }
        float cm = em;
        #pragma unroll
        for (int off = 1; off < 64; off <<= 1) cm = fmaxf(cm, __shfl_xor(cm, off, 64));
        float nm = fmaxf(m, cm);
        float scale = __expf(m - nm);
        ssum *= scale; acc *= scale;
        m = nm;
        float wv = (k < s1) ? __expf(em - nm) : 0.f;
        float ws = wv;
        #pragma unroll
        for (int off = 1; off < 64; off <<= 1) ws += __shfl_xor(ws, off, 64);
        ssum += ws;

        int cnt = s1 - base; if (cnt > 64) cnt = 64;
        int j = 0;
        for (; j + 1 < cnt; j += 2) {
            float w0 = __shfl(wv, j, 64),     w1 = __shfl(wv, j + 1, 64);
            int   p0 = __shfl(p, j, 64),      p1 = __shfl(p, j + 1, 64);
            int sd0 = p0 & 0x7FFFFFFF,        sd1 = p1 & 0x7FFFFFFF;
            const ushort* __restrict__ r0 = (p0 < 0) ? zr : z;
            const ushort* __restrict__ r1 = (p1 < 0) ? zr : z;
            float v0 = bf2f(r0[(size_t)sd0 * OUT_DIM + lane]);
            float v1 = bf2f(r1[(size_t)sd1 * OUT_DIM + lane]);
            acc = fmaf(w0, v0, acc);
            acc = fmaf(w1, v1, acc);
        }
        if (j < cnt) {
            float w0 = __shfl(wv, j, 64);
            int   p0 = __shfl(p, j, 64);
            int sd0 = p0 & 0x7FFFFFFF;
            const ushort* __restrict__ r0 = (p0 < 0) ? zr : z;
            acc = fmaf(w0, bf2f(r0[(size_t)sd0 * OUT_DIM + lane]), acc);
        }
    }

    out[(size_t)node * OUT_DIM + lane] = acc / fmaxf(ssum, 1e-9f);
}

extern "C" void kernel_launch(void* const* d_in, const int* in_sizes, int n_in,
                              void* d_out, int out_size, void* d_ws, size_t ws_size,
                              hipStream_t stream) {
    const float*  h   = (const float*) d_in[0];
    const float*  Wf  = (const float*) d_in[1];
    const float*  Wfr = (const float*) d_in[2];
    const float*  Wa  = (const float*) d_in[3];
    const float2* dir = (const float2*)d_in[4];
    const int*    src = (const int*)   d_in[5];
    const int*    dst = (const int*)   d_in[6];
    float* out = (float*)d_out;

    // ws (4B words): zb zrb | a4 | counts scan start flag | csA deg cursor bsum boff | tmp csr
    ushort*   zb     = (ushort*)d_ws;
    ushort*   zrb    = zb + (size_t)N_NODES * OUT_DIM;
    float4*   a4     = (float4*)(zrb + (size_t)N_NODES * OUT_DIM);
    int*      counts = (int*)(a4 + N_NODES);
    int*      scan   = counts + 38656;
    int*      start  = scan + 38656;
    int*      flag   = start + 50016;
    unsigned* csA    = (unsigned*)(flag + 64);
    int*      deg    = (int*)(csA + N_NODES);
    int*      cursor = deg + N_NODES;
    int*      bsum   = cursor + N_NODES;
    int*      boff   = bsum + 256;
    int2*     tmp    = (int2*)(boff + 256);
    int*      csr    = (int*)(tmp + E_EDGES);

    // csA + deg + cursor are contiguous: one memset
    hipMemsetAsync(csA, 0, (size_t)N_NODES * 3 * sizeof(int), stream);

    const int EB = (E_EDGES + 255) / 256;
    const int GB = (N_NODES + 63) / 64;

    probe_kernel   <<<1, 64, 0, stream>>>(flag);
    node_gemm_mfma <<<GB, 256, 0, stream>>>(h, Wf, Wfr, flag, zb, zrb);
    verify_kernel  <<<32, 256, 0, stream>>>(h, Wf, Wfr, zb, zrb, flag);
    node_gemm_valu <<<GB, 256, 0, stream>>>(h, Wf, Wfr, flag, zb, zrb);
    a4_kernel      <<<(N_NODES * 16 + 255) / 256, 256, 0, stream>>>(zb, zrb, Wa, a4);

    sort_hist      <<<NBLK, 256, 0, stream>>>(dst, counts);
    sort_scan      <<<1, 1024, 0, stream>>>(counts, scan);
    sort_scatter1  <<<NBLK, 256, 0, stream>>>(src, dst, dir, scan, tmp);
    sort_pass2     <<<BUCKETS, 256, 0, stream>>>(scan, tmp, csr, start);

    chk_edges      <<<EB, 256, 0, stream>>>(src, dst, dir, csA);
    chk_csr        <<<(N_NODES + 255) / 256, 256, 0, stream>>>(start, csr, csA, flag);

    fb_hist        <<<EB, 256, 0, stream>>>(dst, deg, flag);
    fb_scan1       <<<SCAN_NB, 256, 0, stream>>>(deg, start, bsum, flag);
    fb_scan2       <<<1, 256, 0, stream>>>(bsum, boff, flag);
    fb_scan3       <<<SCAN_NB, 256, 0, stream>>>(start, boff, flag);
    fb_scatter     <<<EB, 256, 0, stream>>>(src, dst, dir, start, cursor, csr, flag);

    node_aggregate <<<(N_NODES * 64 + 255) / 256, 256, 0, stream>>>(start, csr, a4, zb, zrb, out);
}

// Round 7
// 158.603 us; speedup vs baseline: 1.4352x; 1.4352x over previous
//
#include <hip/hip_runtime.h>

#define N_NODES 50000
#define E_EDGES 800000
#define IN_DIM  128
#define OUT_DIM 64
#define NEG_SLOPE 0.01f
#define SCAN_NB  ((N_NODES + 255) / 256)   // 196
#define LDAP 136                            // padded bf16 row stride

#define BUCKETS 196                         // ceil(N/256): bucket = dst>>8
#define NBLK    196                         // sort blocks
#define CHUNK   4096                        // edges per sort block
#define P2CAP   6144

typedef __attribute__((ext_vector_type(8))) short bf16x8;
typedef __attribute__((ext_vector_type(4))) float f32x4;

__device__ __forceinline__ ushort f2bf(float x) {
    unsigned u = __float_as_uint(x);
    return (ushort)((u + 0x7FFFu + ((u >> 16) & 1u)) >> 16);
}
__device__ __forceinline__ float bf2f(ushort u) {
    return __uint_as_float(((unsigned)u) << 16);
}
__device__ __forceinline__ unsigned edge_hash(unsigned pay) {
    return pay * 2654435761u + 0x9e3779b9u;
}

// flag[0]=probe mapping (0/1/4), flag[1]=verify mismatches, flag[2]=sort-check mismatches
__global__ void probe_kernel(int* flag) {
    int lane = threadIdx.x & 63;
    bf16x8 af = {0,0,0,0,0,0,0,0};
    bf16x8 bf = {0,0,0,0,0,0,0,0};
    if (lane < 16) {
        af[0] = (short)f2bf((float)(1 + lane));
        bf[0] = (short)f2bf((float)((1 + lane) * (1 + lane)));
    }
    f32x4 acc = {0.f, 0.f, 0.f, 0.f};
    acc = __builtin_amdgcn_mfma_f32_16x16x32_bf16(af, bf, acc, 0, 0, 0);
    int lr = lane & 15, lq = lane >> 4;
    bool ok0 = true, ok1 = true;
    #pragma unroll
    for (int r = 0; r < 4; ++r) {
        float e0 = (float)((1 + lq * 4 + r) * (1 + lr) * (1 + lr));
        float e1 = (float)((1 + lr) * (1 + lq * 4 + r) * (1 + lq * 4 + r));
        ok0 = ok0 && (acc[r] == e0);
        ok1 = ok1 && (acc[r] == e1);
    }
    int f = __all(ok0 ? 1 : 0) ? 0 : (__all(ok1 ? 1 : 0) ? 1 : 4);
    if (threadIdx.x == 0) { flag[0] = f; flag[1] = 0; flag[2] = 0; }
}

// ============ MFMA gemm: z/zr only (round-4/6 proven) ============
__global__ __launch_bounds__(256) void node_gemm_mfma(
    const float* __restrict__ h, const float* __restrict__ Wf,
    const float* __restrict__ Wfr, const int* __restrict__ flag,
    ushort* __restrict__ z, ushort* __restrict__ zr)
{
    const int flagv = flag[0];
    if (flagv >= 2) return;

    __shared__ ushort hs [64 * LDAP];
    __shared__ ushort wfs[64 * LDAP];
    __shared__ ushort wrs[64 * LDAP];

    const int t = threadIdx.x;
    const int nb0 = blockIdx.x * 64;

    #pragma unroll
    for (int i = 0; i < 8; ++i) {
        int elem = i * 1024 + t * 4;
        int row = elem >> 7, col = elem & 127;
        int hn = nb0 + row; if (hn >= N_NODES) hn = N_NODES - 1;
        float4 hv = *(const float4*)&h  [(size_t)hn  * IN_DIM + col];
        float4 fv = *(const float4*)&Wf [(size_t)row * IN_DIM + col];
        float4 rv = *(const float4*)&Wfr[(size_t)row * IN_DIM + col];
        ushort4 hu = { f2bf(hv.x), f2bf(hv.y), f2bf(hv.z), f2bf(hv.w) };
        ushort4 fu = { f2bf(fv.x), f2bf(fv.y), f2bf(fv.z), f2bf(fv.w) };
        ushort4 ru = { f2bf(rv.x), f2bf(rv.y), f2bf(rv.z), f2bf(rv.w) };
        *(ushort4*)&hs [row * LDAP + col] = hu;
        *(ushort4*)&wfs[row * LDAP + col] = fu;
        *(ushort4*)&wrs[row * LDAP + col] = ru;
    }
    __syncthreads();

    const int w    = t >> 6;
    const int lane = t & 63;
    const int lr   = lane & 15;
    const int lq   = lane >> 4;

    f32x4 accf[4], accr[4];
    #pragma unroll
    for (int cb = 0; cb < 4; ++cb) {
        accf[cb] = (f32x4){0.f, 0.f, 0.f, 0.f};
        accr[cb] = (f32x4){0.f, 0.f, 0.f, 0.f};
    }

    #pragma unroll
    for (int kc = 0; kc < 4; ++kc) {
        const int koff = kc * 32 + lq * 8;
        bf16x8 af = *(bf16x8*)&hs[(w * 16 + lr) * LDAP + koff];
        #pragma unroll
        for (int cb = 0; cb < 4; ++cb) {
            bf16x8 bfr = *(bf16x8*)&wfs[(cb * 16 + lr) * LDAP + koff];
            bf16x8 brr = *(bf16x8*)&wrs[(cb * 16 + lr) * LDAP + koff];
            accf[cb] = __builtin_amdgcn_mfma_f32_16x16x32_bf16(af, bfr, accf[cb], 0, 0, 0);
            accr[cb] = __builtin_amdgcn_mfma_f32_16x16x32_bf16(af, brr, accr[cb], 0, 0, 0);
        }
    }

    #pragma unroll
    for (int reg = 0; reg < 4; ++reg) {
        const int aIdx = (flagv == 0) ? (lq * 4 + reg) : lr;
        const int bIdx = (flagv == 0) ? lr : (lq * 4 + reg);
        const int node = nb0 + w * 16 + aIdx;
        if (node < N_NODES) {
            #pragma unroll
            for (int cb = 0; cb < 4; ++cb) {
                z [(size_t)node * OUT_DIM + cb * 16 + bIdx] = f2bf(accf[cb][reg]);
                zr[(size_t)node * OUT_DIM + cb * 16 + bIdx] = f2bf(accr[cb][reg]);
            }
        }
    }
}

// ============ verify 8192 sampled z/zr vs fp32 dots ============
__global__ __launch_bounds__(256) void verify_kernel(
    const float* __restrict__ h, const float* __restrict__ Wf,
    const float* __restrict__ Wfr, const ushort* __restrict__ z,
    const ushort* __restrict__ zr, int* __restrict__ flag)
{
    if (flag[0] >= 2) return;
    int i = blockIdx.x * 256 + threadIdx.x;
    unsigned u = (unsigned)i * 2654435761u;
    int n = (int)(u % (unsigned)N_NODES);
    int o = (int)((u >> 17) & 63);
    const ushort* zz = (i & 1) ? zr : z;
    const float*  W  = (i & 1) ? Wfr : Wf;
    float s = 0.f;
    #pragma unroll 4
    for (int k = 0; k < IN_DIM; k += 4) {
        float4 hv = *(const float4*)&h[(size_t)n * IN_DIM + k];
        float4 wv = *(const float4*)&W[(size_t)o * IN_DIM + k];
        s = fmaf(hv.x, wv.x, s); s = fmaf(hv.y, wv.y, s);
        s = fmaf(hv.z, wv.z, s); s = fmaf(hv.w, wv.w, s);
    }
    float zv = bf2f(zz[(size_t)n * OUT_DIM + o]);
    if (fabsf(s - zv) > 0.125f + 0.02f * fabsf(s)) atomicAdd(&flag[1], 1);
}

// ============ VALU fallback gemm (proven) ============
__global__ __launch_bounds__(256) void node_gemm_valu(
    const float* __restrict__ h, const float* __restrict__ Wf,
    const float* __restrict__ Wfr, const int* __restrict__ flag,
    ushort* __restrict__ z, ushort* __restrict__ zr)
{
    if (flag[0] < 2 && flag[1] == 0) return;

    __shared__ float hs [64][33];
    __shared__ float wfs[64][33];
    __shared__ float wrs[64][33];

    const int tid = threadIdx.x;
    const int og = tid & 15;
    const int ng = tid >> 4;
    const int nb0 = blockIdx.x * 64;

    float accf[4][4] = {{0.f}};
    float accr[4][4] = {{0.f}};

    for (int kb = 0; kb < IN_DIM; kb += 32) {
        __syncthreads();
        const int j = tid & 7;
        const int r0 = tid >> 3;
        for (int rr = r0; rr < 64; rr += 32) {
            int hn = nb0 + rr; if (hn >= N_NODES) hn = N_NODES - 1;
            float4 hv = *(const float4*)&h  [(size_t)hn * IN_DIM + kb + j*4];
            float4 fv = *(const float4*)&Wf [(size_t)rr * IN_DIM + kb + j*4];
            float4 rv = *(const float4*)&Wfr[(size_t)rr * IN_DIM + kb + j*4];
            hs [rr][j*4+0] = hv.x; hs [rr][j*4+1] = hv.y; hs [rr][j*4+2] = hv.z; hs [rr][j*4+3] = hv.w;
            wfs[rr][j*4+0] = fv.x; wfs[rr][j*4+1] = fv.y; wfs[rr][j*4+2] = fv.z; wfs[rr][j*4+3] = fv.w;
            wrs[rr][j*4+0] = rv.x; wrs[rr][j*4+1] = rv.y; wrs[rr][j*4+2] = rv.z; wrs[rr][j*4+3] = rv.w;
        }
        __syncthreads();

        #pragma unroll 8
        for (int k = 0; k < 32; ++k) {
            float hv[4], wfv[4], wrv[4];
            #pragma unroll
            for (int i = 0; i < 4; ++i) hv[i] = hs[ng*4+i][k];
            #pragma unroll
            for (int jj = 0; jj < 4; ++jj) { wfv[jj] = wfs[og*4+jj][k]; wrv[jj] = wrs[og*4+jj][k]; }
            #pragma unroll
            for (int i = 0; i < 4; ++i)
                #pragma unroll
                for (int jj = 0; jj < 4; ++jj) {
                    accf[i][jj] = fmaf(hv[i], wfv[jj], accf[i][jj]);
                    accr[i][jj] = fmaf(hv[i], wrv[jj], accr[i][jj]);
                }
        }
    }

    #pragma unroll
    for (int i = 0; i < 4; ++i) {
        const int n = nb0 + ng*4 + i;
        if (n < N_NODES) {
            #pragma unroll
            for (int jj = 0; jj < 4; ++jj) {
                z [(size_t)n*OUT_DIM + og*4 + jj] = f2bf(accf[i][jj]);
                zr[(size_t)n*OUT_DIM + og*4 + jj] = f2bf(accr[i][jj]);
            }
        }
    }
}

// ============ a4 from global z/zr (layout-independent, proven) ============
__global__ __launch_bounds__(256) void a4_kernel(
    const ushort* __restrict__ z, const ushort* __restrict__ zr,
    const float* __restrict__ Wa, float4* __restrict__ a4)
{
    int gid = blockIdx.x * 256 + threadIdx.x;
    int node = gid >> 4;
    int lr = threadIdx.x & 15;
    if (node >= N_NODES) return;
    ushort4 zv = *(const ushort4*)&z [(size_t)node * OUT_DIM + lr * 4];
    ushort4 rv = *(const ushort4*)&zr[(size_t)node * OUT_DIM + lr * 4];
    float4 ws4 = *(const float4*)&Wa[lr * 4];
    float4 wd4 = *(const float4*)&Wa[64 + lr * 4];
    float pSf = bf2f(zv.x)*ws4.x + bf2f(zv.y)*ws4.y + bf2f(zv.z)*ws4.z + bf2f(zv.w)*ws4.w;
    float pDf = bf2f(zv.x)*wd4.x + bf2f(zv.y)*wd4.y + bf2f(zv.z)*wd4.z + bf2f(zv.w)*wd4.w;
    float pSr = bf2f(rv.x)*ws4.x + bf2f(rv.y)*ws4.y + bf2f(rv.z)*ws4.z + bf2f(rv.w)*ws4.w;
    float pDr = bf2f(rv.x)*wd4.x + bf2f(rv.y)*wd4.y + bf2f(rv.z)*wd4.z + bf2f(rv.w)*wd4.w;
    #pragma unroll
    for (int mm = 1; mm < 16; mm <<= 1) {
        pSf += __shfl_xor(pSf, mm, 64);
        pDf += __shfl_xor(pDf, mm, 64);
        pSr += __shfl_xor(pSr, mm, 64);
        pDr += __shfl_xor(pDr, mm, 64);
    }
    if (lr == 0) a4[node] = make_float4(pSf, pDf, pSr, pDr);
}

// ============ sort chain (checksum-validated) ============
__global__ __launch_bounds__(256) void sort_hist(
    const int* __restrict__ dst, int* __restrict__ counts)
{
    __shared__ int bh[BUCKETS];
    const int b = blockIdx.x;
    for (int i = threadIdx.x; i < BUCKETS; i += 256) bh[i] = 0;
    __syncthreads();
    const int base = b * CHUNK;
    const int end = (base + CHUNK < E_EDGES) ? base + CHUNK : E_EDGES;
    for (int i = base + threadIdx.x; i < end; i += 256)
        atomicAdd(&bh[dst[i] >> 8], 1);
    __syncthreads();
    for (int i = threadIdx.x; i < BUCKETS; i += 256)
        counts[i * NBLK + b] = bh[i];
}

// per-bucket exclusive scan of block-counts; also bucket totals
__global__ __launch_bounds__(256) void sort_scanA(
    const int* __restrict__ counts, int* __restrict__ scanw, int* __restrict__ btot)
{
    __shared__ int tmp[256];
    const int j = blockIdx.x;
    const int t = threadIdx.x;
    int v = (t < NBLK) ? counts[j * NBLK + t] : 0;
    tmp[t] = v; __syncthreads();
    #pragma unroll
    for (int off = 1; off < 256; off <<= 1) {
        int u = (t >= off) ? tmp[t - off] : 0;
        __syncthreads();
        tmp[t] += u;
        __syncthreads();
    }
    if (t < NBLK) scanw[j * NBLK + t] = tmp[t] - v;
    if (t == 255) btot[j] = tmp[t];
}

// exclusive scan of bucket totals -> bbase[0..BUCKETS], sentinel at BUCKETS
__global__ __launch_bounds__(256) void sort_scanB(
    const int* __restrict__ btot, int* __restrict__ bbase)
{
    __shared__ int tmp[256];
    const int t = threadIdx.x;
    int v = (t < BUCKETS) ? btot[t] : 0;
    tmp[t] = v; __syncthreads();
    #pragma unroll
    for (int off = 1; off < 256; off <<= 1) {
        int u = (t >= off) ? tmp[t - off] : 0;
        __syncthreads();
        tmp[t] += u;
        __syncthreads();
    }
    if (t < BUCKETS) bbase[t] = tmp[t] - v;
    if (t == 255) bbase[BUCKETS] = tmp[t];
}

__global__ __launch_bounds__(256) void sort_scatter1(
    const int* __restrict__ src, const int* __restrict__ dst,
    const float2* __restrict__ dir, const int* __restrict__ scanw,
    const int* __restrict__ bbase, int2* __restrict__ tmpbuf)
{
    __shared__ int2 recs[CHUNK];
    __shared__ int bh[BUCKETS];
    __shared__ int sc[256];
    __shared__ int cur[BUCKETS];

    const int b = blockIdx.x;
    const int t = threadIdx.x;
    const int base = b * CHUNK;
    const int end = (base + CHUNK < E_EDGES) ? base + CHUNK : E_EDGES;
    const int cnt = end - base;

    for (int i = t; i < BUCKETS; i += 256) bh[i] = 0;
    __syncthreads();

    for (int i = t; i < cnt; i += 256) {
        int e = base + i;
        int d = dst[e];
        float2 dd = dir[e];
        int pay = src[e] | ((dd.y != 0.f) ? 0x80000000 : 0);
        recs[i] = make_int2(pay, d);
        atomicAdd(&bh[d >> 8], 1);
    }
    __syncthreads();

    sc[t] = (t < BUCKETS) ? bh[t] : 0;
    __syncthreads();
    for (int off = 1; off < 256; off <<= 1) {
        int v = (t >= off) ? sc[t - off] : 0;
        __syncthreads();
        sc[t] += v;
        __syncthreads();
    }
    if (t < BUCKETS) cur[t] = (t > 0) ? sc[t - 1] : 0;
    __syncthreads();

    for (int i = t; i < cnt; i += 256) {
        int2 r = recs[i];
        int bkt = r.y >> 8;
        int loc = atomicAdd(&cur[bkt], 1);
        int lbase = (bkt > 0) ? sc[bkt - 1] : 0;
        tmpbuf[scanw[bkt * NBLK + b] + bbase[bkt] + (loc - lbase)] = r;
    }
}

__global__ __launch_bounds__(256) void sort_pass2(
    const int* __restrict__ bbase, const int2* __restrict__ tmpbuf,
    int* __restrict__ csr, int* __restrict__ start)
{
    __shared__ int nh[256];
    __shared__ int nex[256];
    __shared__ int ncur[256];
    __shared__ int2 recs[P2CAP];

    const int j = blockIdx.x;
    const int t = threadIdx.x;
    const int gbeg = bbase[j];
    const int gend = bbase[j + 1];
    const int cnt = gend - gbeg;
    const bool fits = (cnt <= P2CAP);

    nh[t] = 0;
    __syncthreads();

    for (int i = t; i < cnt; i += 256) {
        int2 r = tmpbuf[gbeg + i];
        if (fits) recs[i] = r;
        atomicAdd(&nh[r.y & 255], 1);
    }
    __syncthreads();

    nex[t] = nh[t];
    __syncthreads();
    for (int off = 1; off < 256; off <<= 1) {
        int v = (t >= off) ? nex[t - off] : 0;
        __syncthreads();
        nex[t] += v;
        __syncthreads();
    }
    int excl = (t > 0) ? nex[t - 1] : 0;
    ncur[t] = excl;
    const int node = j * 256 + t;
    if (node < N_NODES) start[node] = gbeg + excl;
    if (j == BUCKETS - 1 && t == 0) start[N_NODES] = E_EDGES;
    __syncthreads();

    for (int i = t; i < cnt; i += 256) {
        int2 r = fits ? recs[i] : tmpbuf[gbeg + i];
        int lid = r.y & 255;
        int loc = atomicAdd(&ncur[lid], 1);
        csr[gbeg + loc] = r.x;
    }
}

// ============ CSR checksum validation ============
__global__ __launch_bounds__(256) void chk_edges(
    const int* __restrict__ src, const int* __restrict__ dst,
    const float2* __restrict__ dir, unsigned* __restrict__ csA)
{
    int e = blockIdx.x * 256 + threadIdx.x;
    if (e >= E_EDGES) return;
    unsigned pay = (unsigned)src[e] | ((dir[e].y != 0.f) ? 0x80000000u : 0u);
    atomicAdd(&csA[dst[e]], edge_hash(pay));
}

__global__ __launch_bounds__(256) void chk_csr(
    const int* __restrict__ start, const int* __restrict__ csr,
    const unsigned* __restrict__ csA, int* __restrict__ flag)
{
    int n = blockIdx.x * 256 + threadIdx.x;
    if (n >= N_NODES) return;
    int s = start[n], e1 = start[n + 1];
    if (s < 0 || e1 < s || e1 > E_EDGES || (n == 0 && s != 0)) {
        atomicAdd(&flag[2], 1); return;
    }
    unsigned acc = 0;
    for (int k = s; k < e1; ++k) acc += edge_hash((unsigned)csr[k]);
    if (acc != csA[n]) atomicAdd(&flag[2], 1);
}

// ============ guarded fallback: proven CSR build ============
__global__ __launch_bounds__(256) void fb_hist(
    const int* __restrict__ dst, int* __restrict__ deg, const int* __restrict__ flag)
{
    if (flag[2] == 0) return;
    int e = blockIdx.x * 256 + threadIdx.x;
    if (e < E_EDGES) atomicAdd(&deg[dst[e]], 1);
}

__global__ __launch_bounds__(256) void fb_scan1(
    const int* __restrict__ deg, int* __restrict__ excl, int* __restrict__ bsum,
    const int* __restrict__ flag)
{
    if (flag[2] == 0) return;
    __shared__ int tmp[256];
    int tid = threadIdx.x;
    int i = blockIdx.x * 256 + tid;
    int v = (i < N_NODES) ? deg[i] : 0;
    tmp[tid] = v; __syncthreads();
    #pragma unroll
    for (int off = 1; off < 256; off <<= 1) {
        int t = (tid >= off) ? tmp[tid - off] : 0;
        __syncthreads();
        tmp[tid] += t;
        __syncthreads();
    }
    if (i < N_NODES) excl[i] = tmp[tid] - v;
    if (tid == 255) bsum[blockIdx.x] = tmp[tid];
}

__global__ __launch_bounds__(256) void fb_scan2(
    const int* __restrict__ bsum, int* __restrict__ boff, const int* __restrict__ flag)
{
    if (flag[2] == 0) return;
    __shared__ int tmp[256];
    int tid = threadIdx.x;
    int v = (tid < SCAN_NB) ? bsum[tid] : 0;
    tmp[tid] = v; __syncthreads();
    #pragma unroll
    for (int off = 1; off < 256; off <<= 1) {
        int t = (tid >= off) ? tmp[tid - off] : 0;
        __syncthreads();
        tmp[tid] += t;
        __syncthreads();
    }
    if (tid < SCAN_NB) boff[tid] = tmp[tid] - v;
}

__global__ __launch_bounds__(256) void fb_scan3(
    int* __restrict__ excl, const int* __restrict__ boff, const int* __restrict__ flag)
{
    if (flag[2] == 0) return;
    int i = blockIdx.x * 256 + threadIdx.x;
    if (i < N_NODES) excl[i] += boff[blockIdx.x];
    if (i == 0) excl[N_NODES] = E_EDGES;
}

__global__ __launch_bounds__(256) void fb_scatter(
    const int* __restrict__ src, const int* __restrict__ dst,
    const float2* __restrict__ dir, const int* __restrict__ start,
    int* __restrict__ cursor, int* __restrict__ csr, const int* __restrict__ flag)
{
    if (flag[2] == 0) return;
    int e = blockIdx.x * 256 + threadIdx.x;
    if (e >= E_EDGES) return;
    int dd = dst[e];
    int pos = atomicAdd(&cursor[dd], 1);
    float2 d = dir[e];
    int packed = src[e] | ((d.y != 0.f) ? 0x80000000 : 0);
    csr[start[dd] + pos] = packed;
}

// ============ fused softmax+aggregate: wave/node, 4 edges per inner iter ============
__global__ __launch_bounds__(256) void node_aggregate(
    const int* __restrict__ start, const int* __restrict__ csr,
    const float4* __restrict__ a4, const ushort* __restrict__ z,
    const ushort* __restrict__ zr, float* __restrict__ out)
{
    int gid = blockIdx.x * 256 + threadIdx.x;
    int node = gid >> 6;
    int lane = threadIdx.x & 63;
    int l = lane & 15;      // channel quad: cols l*4..l*4+3
    int g = lane >> 4;      // edge slot 0..3
    if (node >= N_NODES) return;

    const int s0 = start[node];
    const int s1 = start[node + 1];
    const float4 an = a4[node];

    float m = -__builtin_inff();
    float ssum = 0.f;
    float ax = 0.f, ay = 0.f, az = 0.f, aw = 0.f;

    for (int base = s0; base < s1; base += 64) {
        // phase 1 (proven): per-lane logit, wave max/sum
        int k = base + lane;
        int p = 0;
        float em = -__builtin_inff();
        if (k < s1) {
            p = csr[k];
            int sd = p & 0x7FFFFFFF;
            float4 a = a4[sd];
            float tl = (p < 0) ? (a.z + an.w) : (a.x + an.y);
            em = (tl > 0.f) ? tl : NEG_SLOPE * tl;
        }
        float cm = em;
        #pragma unroll
        for (int off = 1; off < 64; off <<= 1) cm = fmaxf(cm, __shfl_xor(cm, off, 64));
        float nm = fmaxf(m, cm);
        float scale = __expf(m - nm);
        ssum *= scale; ax *= scale; ay *= scale; az *= scale; aw *= scale;
        m = nm;
        float wv = (k < s1) ? __expf(em - nm) : 0.f;
        float ws = wv;
        #pragma unroll
        for (int off = 1; off < 64; off <<= 1) ws += __shfl_xor(ws, off, 64);
        ssum += ws;

        // phase 2: 4 edges per iteration; 16-lane group g handles edge j+g
        int cnt = s1 - base; if (cnt > 64) cnt = 64;
        for (int j = 0; j < cnt; j += 4) {
            int jj = j + g;                       // <= 63 always (j <= 60)
            float wj = __shfl(wv, jj, 64);
            int   pj = __shfl(p,  jj, 64);
            if (jj < cnt) {
                int sdj = pj & 0x7FFFFFFF;
                const ushort* __restrict__ row = (pj < 0) ? zr : z;
                ushort4 v = *(const ushort4*)&row[(size_t)sdj * OUT_DIM + l * 4];
                ax = fmaf(wj, bf2f(v.x), ax);
                ay = fmaf(wj, bf2f(v.y), ay);
                az = fmaf(wj, bf2f(v.z), az);
                aw = fmaf(wj, bf2f(v.w), aw);
            }
        }
    }

    // reduce partials across the 4 edge-slot groups (lane bits 4,5)
    ax += __shfl_xor(ax, 16, 64); ax += __shfl_xor(ax, 32, 64);
    ay += __shfl_xor(ay, 16, 64); ay += __shfl_xor(ay, 32, 64);
    az += __shfl_xor(az, 16, 64); az += __shfl_xor(az, 32, 64);
    aw += __shfl_xor(aw, 16, 64); aw += __shfl_xor(aw, 32, 64);

    float inv = 1.f / fmaxf(ssum, 1e-9f);
    if (g == 0)
        *(float4*)&out[(size_t)node * OUT_DIM + l * 4] =
            make_float4(ax * inv, ay * inv, az * inv, aw * inv);
}

extern "C" void kernel_launch(void* const* d_in, const int* in_sizes, int n_in,
                              void* d_out, int out_size, void* d_ws, size_t ws_size,
                              hipStream_t stream) {
    const float*  h   = (const float*) d_in[0];
    const float*  Wf  = (const float*) d_in[1];
    const float*  Wfr = (const float*) d_in[2];
    const float*  Wa  = (const float*) d_in[3];
    const float2* dir = (const float2*)d_in[4];
    const int*    src = (const int*)   d_in[5];
    const int*    dst = (const int*)   d_in[6];
    float* out = (float*)d_out;

    // ws (4B words): zb zrb | a4 | counts scanw bbase btot start flag | csA deg cursor bsum boff | tmp csr
    ushort*   zb     = (ushort*)d_ws;
    ushort*   zrb    = zb + (size_t)N_NODES * OUT_DIM;
    float4*   a4     = (float4*)(zrb + (size_t)N_NODES * OUT_DIM);
    int*      counts = (int*)(a4 + N_NODES);
    int*      scanw  = counts + 38656;
    int*      bbase  = scanw + 38656;
    int*      btot   = bbase + 256;
    int*      start  = btot + 256;
    int*      flag   = start + 50016;
    unsigned* csA    = (unsigned*)(flag + 64);
    int*      deg    = (int*)(csA + N_NODES);
    int*      cursor = deg + N_NODES;
    int*      bsum   = cursor + N_NODES;
    int*      boff   = bsum + 256;
    int2*     tmp    = (int2*)(boff + 256);
    int*      csr    = (int*)(tmp + E_EDGES);

    hipMemsetAsync(csA, 0, (size_t)N_NODES * 3 * sizeof(int), stream);  // csA+deg+cursor

    const int EB = (E_EDGES + 255) / 256;
    const int GB = (N_NODES + 63) / 64;

    probe_kernel   <<<1, 64, 0, stream>>>(flag);
    node_gemm_mfma <<<GB, 256, 0, stream>>>(h, Wf, Wfr, flag, zb, zrb);
    verify_kernel  <<<32, 256, 0, stream>>>(h, Wf, Wfr, zb, zrb, flag);
    node_gemm_valu <<<GB, 256, 0, stream>>>(h, Wf, Wfr, flag, zb, zrb);
    a4_kernel      <<<(N_NODES * 16 + 255) / 256, 256, 0, stream>>>(zb, zrb, Wa, a4);

    sort_hist      <<<NBLK, 256, 0, stream>>>(dst, counts);
    sort_scanA     <<<BUCKETS, 256, 0, stream>>>(counts, scanw, btot);
    sort_scanB     <<<1, 256, 0, stream>>>(btot, bbase);
    sort_scatter1  <<<NBLK, 256, 0, stream>>>(src, dst, dir, scanw, bbase, tmp);
    sort_pass2     <<<BUCKETS, 256, 0, stream>>>(bbase, tmp, csr, start);

    chk_edges      <<<EB, 256, 0, stream>>>(src, dst, dir, csA);
    chk_csr        <<<(N_NODES + 255) / 256, 256, 0, stream>>>(start, csr, csA, flag);

    fb_hist        <<<EB, 256, 0, stream>>>(dst, deg, flag);
    fb_scan1       <<<SCAN_NB, 256, 0, stream>>>(deg, start, bsum, flag);
    fb_scan2       <<<1, 256, 0, stream>>>(bsum, boff, flag);
    fb_scan3       <<<SCAN_NB, 256, 0, stream>>>(start, boff, flag);
    fb_scatter     <<<EB, 256, 0, stream>>>(src, dst, dir, start, cursor, csr, flag);

    node_aggregate <<<(N_NODES * 64 + 255) / 256, 256, 0, stream>>>(start, csr, a4, zb, zrb, out);
}

// Round 8
// 105.580 us; speedup vs baseline: 2.1559x; 1.5022x over previous
//
#include <hip/hip_runtime.h>

#define N_NODES 50000
#define E_EDGES 800000
#define IN_DIM  128
#define OUT_DIM 64
#define NEG_SLOPE 0.01f
#define LDAP 136                            // padded bf16 row stride

#define BUCKETS 196                         // ceil(N/256): bucket = dst>>8
#define NBLK    196                         // sort blocks
#define CHUNK   4096                        // edges per sort block
#define P2CAP   6144

typedef __attribute__((ext_vector_type(8))) short bf16x8;
typedef __attribute__((ext_vector_type(4))) float f32x4;

__device__ __forceinline__ ushort f2bf(float x) {
    unsigned u = __float_as_uint(x);
    return (ushort)((u + 0x7FFFu + ((u >> 16) & 1u)) >> 16);
}
__device__ __forceinline__ float bf2f(ushort u) {
    return __uint_as_float(((unsigned)u) << 16);
}

// flag[0]=probe mapping (0/1/4), flag[1]=verify mismatches
__global__ void probe_kernel(int* flag) {
    int lane = threadIdx.x & 63;
    bf16x8 af = {0,0,0,0,0,0,0,0};
    bf16x8 bf = {0,0,0,0,0,0,0,0};
    if (lane < 16) {
        af[0] = (short)f2bf((float)(1 + lane));
        bf[0] = (short)f2bf((float)((1 + lane) * (1 + lane)));
    }
    f32x4 acc = {0.f, 0.f, 0.f, 0.f};
    acc = __builtin_amdgcn_mfma_f32_16x16x32_bf16(af, bf, acc, 0, 0, 0);
    int lr = lane & 15, lq = lane >> 4;
    bool ok0 = true, ok1 = true;
    #pragma unroll
    for (int r = 0; r < 4; ++r) {
        float e0 = (float)((1 + lq * 4 + r) * (1 + lr) * (1 + lr));
        float e1 = (float)((1 + lr) * (1 + lq * 4 + r) * (1 + lq * 4 + r));
        ok0 = ok0 && (acc[r] == e0);
        ok1 = ok1 && (acc[r] == e1);
    }
    int f = __all(ok0 ? 1 : 0) ? 0 : (__all(ok1 ? 1 : 0) ? 1 : 4);
    if (threadIdx.x == 0) { flag[0] = f; flag[1] = 0; }
}

// ============ MFMA gemm: z/zr (proven r4/r6/r7) ============
__global__ __launch_bounds__(256) void node_gemm_mfma(
    const float* __restrict__ h, const float* __restrict__ Wf,
    const float* __restrict__ Wfr, const int* __restrict__ flag,
    ushort* __restrict__ z, ushort* __restrict__ zr)
{
    const int flagv = flag[0];
    if (flagv >= 2) return;

    __shared__ ushort hs [64 * LDAP];
    __shared__ ushort wfs[64 * LDAP];
    __shared__ ushort wrs[64 * LDAP];

    const int t = threadIdx.x;
    const int nb0 = blockIdx.x * 64;

    #pragma unroll
    for (int i = 0; i < 8; ++i) {
        int elem = i * 1024 + t * 4;
        int row = elem >> 7, col = elem & 127;
        int hn = nb0 + row; if (hn >= N_NODES) hn = N_NODES - 1;
        float4 hv = *(const float4*)&h  [(size_t)hn  * IN_DIM + col];
        float4 fv = *(const float4*)&Wf [(size_t)row * IN_DIM + col];
        float4 rv = *(const float4*)&Wfr[(size_t)row * IN_DIM + col];
        ushort4 hu = { f2bf(hv.x), f2bf(hv.y), f2bf(hv.z), f2bf(hv.w) };
        ushort4 fu = { f2bf(fv.x), f2bf(fv.y), f2bf(fv.z), f2bf(fv.w) };
        ushort4 ru = { f2bf(rv.x), f2bf(rv.y), f2bf(rv.z), f2bf(rv.w) };
        *(ushort4*)&hs [row * LDAP + col] = hu;
        *(ushort4*)&wfs[row * LDAP + col] = fu;
        *(ushort4*)&wrs[row * LDAP + col] = ru;
    }
    __syncthreads();

    const int w    = t >> 6;
    const int lane = t & 63;
    const int lr   = lane & 15;
    const int lq   = lane >> 4;

    f32x4 accf[4], accr[4];
    #pragma unroll
    for (int cb = 0; cb < 4; ++cb) {
        accf[cb] = (f32x4){0.f, 0.f, 0.f, 0.f};
        accr[cb] = (f32x4){0.f, 0.f, 0.f, 0.f};
    }

    #pragma unroll
    for (int kc = 0; kc < 4; ++kc) {
        const int koff = kc * 32 + lq * 8;
        bf16x8 af = *(bf16x8*)&hs[(w * 16 + lr) * LDAP + koff];
        #pragma unroll
        for (int cb = 0; cb < 4; ++cb) {
            bf16x8 bfr = *(bf16x8*)&wfs[(cb * 16 + lr) * LDAP + koff];
            bf16x8 brr = *(bf16x8*)&wrs[(cb * 16 + lr) * LDAP + koff];
            accf[cb] = __builtin_amdgcn_mfma_f32_16x16x32_bf16(af, bfr, accf[cb], 0, 0, 0);
            accr[cb] = __builtin_amdgcn_mfma_f32_16x16x32_bf16(af, brr, accr[cb], 0, 0, 0);
        }
    }

    #pragma unroll
    for (int reg = 0; reg < 4; ++reg) {
        const int aIdx = (flagv == 0) ? (lq * 4 + reg) : lr;
        const int bIdx = (flagv == 0) ? lr : (lq * 4 + reg);
        const int node = nb0 + w * 16 + aIdx;
        if (node < N_NODES) {
            #pragma unroll
            for (int cb = 0; cb < 4; ++cb) {
                z [(size_t)node * OUT_DIM + cb * 16 + bIdx] = f2bf(accf[cb][reg]);
                zr[(size_t)node * OUT_DIM + cb * 16 + bIdx] = f2bf(accr[cb][reg]);
            }
        }
    }
}

// ============ verify 8192 sampled z/zr vs fp32 dots ============
__global__ __launch_bounds__(256) void verify_kernel(
    const float* __restrict__ h, const float* __restrict__ Wf,
    const float* __restrict__ Wfr, const ushort* __restrict__ z,
    const ushort* __restrict__ zr, int* __restrict__ flag)
{
    if (flag[0] >= 2) return;
    int i = blockIdx.x * 256 + threadIdx.x;
    unsigned u = (unsigned)i * 2654435761u;
    int n = (int)(u % (unsigned)N_NODES);
    int o = (int)((u >> 17) & 63);
    const ushort* zz = (i & 1) ? zr : z;
    const float*  W  = (i & 1) ? Wfr : Wf;
    float s = 0.f;
    #pragma unroll 4
    for (int k = 0; k < IN_DIM; k += 4) {
        float4 hv = *(const float4*)&h[(size_t)n * IN_DIM + k];
        float4 wv = *(const float4*)&W[(size_t)o * IN_DIM + k];
        s = fmaf(hv.x, wv.x, s); s = fmaf(hv.y, wv.y, s);
        s = fmaf(hv.z, wv.z, s); s = fmaf(hv.w, wv.w, s);
    }
    float zv = bf2f(zz[(size_t)n * OUT_DIM + o]);
    if (fabsf(s - zv) > 0.125f + 0.02f * fabsf(s)) atomicAdd(&flag[1], 1);
}

// ============ VALU fallback gemm (proven) ============
__global__ __launch_bounds__(256) void node_gemm_valu(
    const float* __restrict__ h, const float* __restrict__ Wf,
    const float* __restrict__ Wfr, const int* __restrict__ flag,
    ushort* __restrict__ z, ushort* __restrict__ zr)
{
    if (flag[0] < 2 && flag[1] == 0) return;

    __shared__ float hs [64][33];
    __shared__ float wfs[64][33];
    __shared__ float wrs[64][33];

    const int tid = threadIdx.x;
    const int og = tid & 15;
    const int ng = tid >> 4;
    const int nb0 = blockIdx.x * 64;

    float accf[4][4] = {{0.f}};
    float accr[4][4] = {{0.f}};

    for (int kb = 0; kb < IN_DIM; kb += 32) {
        __syncthreads();
        const int j = tid & 7;
        const int r0 = tid >> 3;
        for (int rr = r0; rr < 64; rr += 32) {
            int hn = nb0 + rr; if (hn >= N_NODES) hn = N_NODES - 1;
            float4 hv = *(const float4*)&h  [(size_t)hn * IN_DIM + kb + j*4];
            float4 fv = *(const float4*)&Wf [(size_t)rr * IN_DIM + kb + j*4];
            float4 rv = *(const float4*)&Wfr[(size_t)rr * IN_DIM + kb + j*4];
            hs [rr][j*4+0] = hv.x; hs [rr][j*4+1] = hv.y; hs [rr][j*4+2] = hv.z; hs [rr][j*4+3] = hv.w;
            wfs[rr][j*4+0] = fv.x; wfs[rr][j*4+1] = fv.y; wfs[rr][j*4+2] = fv.z; wfs[rr][j*4+3] = fv.w;
            wrs[rr][j*4+0] = rv.x; wrs[rr][j*4+1] = rv.y; wrs[rr][j*4+2] = rv.z; wrs[rr][j*4+3] = rv.w;
        }
        __syncthreads();

        #pragma unroll 8
        for (int k = 0; k < 32; ++k) {
            float hv[4], wfv[4], wrv[4];
            #pragma unroll
            for (int i = 0; i < 4; ++i) hv[i] = hs[ng*4+i][k];
            #pragma unroll
            for (int jj = 0; jj < 4; ++jj) { wfv[jj] = wfs[og*4+jj][k]; wrv[jj] = wrs[og*4+jj][k]; }
            #pragma unroll
            for (int i = 0; i < 4; ++i)
                #pragma unroll
                for (int jj = 0; jj < 4; ++jj) {
                    accf[i][jj] = fmaf(hv[i], wfv[jj], accf[i][jj]);
                    accr[i][jj] = fmaf(hv[i], wrv[jj], accr[i][jj]);
                }
        }
    }

    #pragma unroll
    for (int i = 0; i < 4; ++i) {
        const int n = nb0 + ng*4 + i;
        if (n < N_NODES) {
            #pragma unroll
            for (int jj = 0; jj < 4; ++jj) {
                z [(size_t)n*OUT_DIM + og*4 + jj] = f2bf(accf[i][jj]);
                zr[(size_t)n*OUT_DIM + og*4 + jj] = f2bf(accr[i][jj]);
            }
        }
    }
}

// ============ a4 from global z/zr (layout-independent, proven) ============
__global__ __launch_bounds__(256) void a4_kernel(
    const ushort* __restrict__ z, const ushort* __restrict__ zr,
    const float* __restrict__ Wa, float4* __restrict__ a4)
{
    int gid = blockIdx.x * 256 + threadIdx.x;
    int node = gid >> 4;
    int lr = threadIdx.x & 15;
    if (node >= N_NODES) return;
    ushort4 zv = *(const ushort4*)&z [(size_t)node * OUT_DIM + lr * 4];
    ushort4 rv = *(const ushort4*)&zr[(size_t)node * OUT_DIM + lr * 4];
    float4 ws4 = *(const float4*)&Wa[lr * 4];
    float4 wd4 = *(const float4*)&Wa[64 + lr * 4];
    float pSf = bf2f(zv.x)*ws4.x + bf2f(zv.y)*ws4.y + bf2f(zv.z)*ws4.z + bf2f(zv.w)*ws4.w;
    float pDf = bf2f(zv.x)*wd4.x + bf2f(zv.y)*wd4.y + bf2f(zv.z)*wd4.z + bf2f(zv.w)*wd4.w;
    float pSr = bf2f(rv.x)*ws4.x + bf2f(rv.y)*ws4.y + bf2f(rv.z)*ws4.z + bf2f(rv.w)*ws4.w;
    float pDr = bf2f(rv.x)*wd4.x + bf2f(rv.y)*wd4.y + bf2f(rv.z)*wd4.z + bf2f(rv.w)*wd4.w;
    #pragma unroll
    for (int mm = 1; mm < 16; mm <<= 1) {
        pSf += __shfl_xor(pSf, mm, 64);
        pDf += __shfl_xor(pDf, mm, 64);
        pSr += __shfl_xor(pSr, mm, 64);
        pDr += __shfl_xor(pDr, mm, 64);
    }
    if (lr == 0) a4[node] = make_float4(pSf, pDf, pSr, pDr);
}

// ============ sort chain (deterministic by construction; validated r6+r7) ============
__global__ __launch_bounds__(256) void sort_hist(
    const int* __restrict__ dst, int* __restrict__ counts)
{
    __shared__ int bh[BUCKETS];
    const int b = blockIdx.x;
    for (int i = threadIdx.x; i < BUCKETS; i += 256) bh[i] = 0;
    __syncthreads();
    const int base = b * CHUNK;
    const int end = (base + CHUNK < E_EDGES) ? base + CHUNK : E_EDGES;
    for (int i = base + threadIdx.x; i < end; i += 256)
        atomicAdd(&bh[dst[i] >> 8], 1);
    __syncthreads();
    for (int i = threadIdx.x; i < BUCKETS; i += 256)
        counts[i * NBLK + b] = bh[i];
}

__global__ __launch_bounds__(256) void sort_scanA(
    const int* __restrict__ counts, int* __restrict__ scanw, int* __restrict__ btot)
{
    __shared__ int tmp[256];
    const int j = blockIdx.x;
    const int t = threadIdx.x;
    int v = (t < NBLK) ? counts[j * NBLK + t] : 0;
    tmp[t] = v; __syncthreads();
    #pragma unroll
    for (int off = 1; off < 256; off <<= 1) {
        int u = (t >= off) ? tmp[t - off] : 0;
        __syncthreads();
        tmp[t] += u;
        __syncthreads();
    }
    if (t < NBLK) scanw[j * NBLK + t] = tmp[t] - v;
    if (t == 255) btot[j] = tmp[t];
}

__global__ __launch_bounds__(256) void sort_scanB(
    const int* __restrict__ btot, int* __restrict__ bbase)
{
    __shared__ int tmp[256];
    const int t = threadIdx.x;
    int v = (t < BUCKETS) ? btot[t] : 0;
    tmp[t] = v; __syncthreads();
    #pragma unroll
    for (int off = 1; off < 256; off <<= 1) {
        int u = (t >= off) ? tmp[t - off] : 0;
        __syncthreads();
        tmp[t] += u;
        __syncthreads();
    }
    if (t < BUCKETS) bbase[t] = tmp[t] - v;
    if (t == 255) bbase[BUCKETS] = tmp[t];
}

__global__ __launch_bounds__(256) void sort_scatter1(
    const int* __restrict__ src, const int* __restrict__ dst,
    const float2* __restrict__ dir, const int* __restrict__ scanw,
    const int* __restrict__ bbase, int2* __restrict__ tmpbuf)
{
    __shared__ int2 recs[CHUNK];
    __shared__ int bh[BUCKETS];
    __shared__ int sc[256];
    __shared__ int cur[BUCKETS];

    const int b = blockIdx.x;
    const int t = threadIdx.x;
    const int base = b * CHUNK;
    const int end = (base + CHUNK < E_EDGES) ? base + CHUNK : E_EDGES;
    const int cnt = end - base;

    for (int i = t; i < BUCKETS; i += 256) bh[i] = 0;
    __syncthreads();

    for (int i = t; i < cnt; i += 256) {
        int e = base + i;
        int d = dst[e];
        float2 dd = dir[e];
        int pay = src[e] | ((dd.y != 0.f) ? 0x80000000 : 0);
        recs[i] = make_int2(pay, d);
        atomicAdd(&bh[d >> 8], 1);
    }
    __syncthreads();

    sc[t] = (t < BUCKETS) ? bh[t] : 0;
    __syncthreads();
    for (int off = 1; off < 256; off <<= 1) {
        int v = (t >= off) ? sc[t - off] : 0;
        __syncthreads();
        sc[t] += v;
        __syncthreads();
    }
    if (t < BUCKETS) cur[t] = (t > 0) ? sc[t - 1] : 0;
    __syncthreads();

    for (int i = t; i < cnt; i += 256) {
        int2 r = recs[i];
        int bkt = r.y >> 8;
        int loc = atomicAdd(&cur[bkt], 1);
        int lbase = (bkt > 0) ? sc[bkt - 1] : 0;
        tmpbuf[scanw[bkt * NBLK + b] + bbase[bkt] + (loc - lbase)] = r;
    }
}

__global__ __launch_bounds__(256) void sort_pass2(
    const int* __restrict__ bbase, const int2* __restrict__ tmpbuf,
    int* __restrict__ csr, int* __restrict__ start)
{
    __shared__ int nh[256];
    __shared__ int nex[256];
    __shared__ int ncur[256];
    __shared__ int2 recs[P2CAP];

    const int j = blockIdx.x;
    const int t = threadIdx.x;
    const int gbeg = bbase[j];
    const int gend = bbase[j + 1];
    const int cnt = gend - gbeg;
    const bool fits = (cnt <= P2CAP);

    nh[t] = 0;
    __syncthreads();

    for (int i = t; i < cnt; i += 256) {
        int2 r = tmpbuf[gbeg + i];
        if (fits) recs[i] = r;
        atomicAdd(&nh[r.y & 255], 1);
    }
    __syncthreads();

    nex[t] = nh[t];
    __syncthreads();
    for (int off = 1; off < 256; off <<= 1) {
        int v = (t >= off) ? nex[t - off] : 0;
        __syncthreads();
        nex[t] += v;
        __syncthreads();
    }
    int excl = (t > 0) ? nex[t - 1] : 0;
    ncur[t] = excl;
    const int node = j * 256 + t;
    if (node < N_NODES) start[node] = gbeg + excl;
    if (j == BUCKETS - 1 && t == 0) start[N_NODES] = E_EDGES;
    __syncthreads();

    for (int i = t; i < cnt; i += 256) {
        int2 r = fits ? recs[i] : tmpbuf[gbeg + i];
        int lid = r.y & 255;
        int loc = atomicAdd(&ncur[lid], 1);
        csr[gbeg + loc] = r.x;
    }
}

// ============ fused softmax+aggregate (proven r7) ============
__global__ __launch_bounds__(256) void node_aggregate(
    const int* __restrict__ start, const int* __restrict__ csr,
    const float4* __restrict__ a4, const ushort* __restrict__ z,
    const ushort* __restrict__ zr, float* __restrict__ out)
{
    int gid = blockIdx.x * 256 + threadIdx.x;
    int node = gid >> 6;
    int lane = threadIdx.x & 63;
    int l = lane & 15;      // channel quad: cols l*4..l*4+3
    int g = lane >> 4;      // edge slot 0..3
    if (node >= N_NODES) return;

    const int s0 = start[node];
    const int s1 = start[node + 1];
    const float4 an = a4[node];

    float m = -__builtin_inff();
    float ssum = 0.f;
    float ax = 0.f, ay = 0.f, az = 0.f, aw = 0.f;

    for (int base = s0; base < s1; base += 64) {
        int k = base + lane;
        int p = 0;
        float em = -__builtin_inff();
        if (k < s1) {
            p = csr[k];
            int sd = p & 0x7FFFFFFF;
            float4 a = a4[sd];
            float tl = (p < 0) ? (a.z + an.w) : (a.x + an.y);
            em = (tl > 0.f) ? tl : NEG_SLOPE * tl;
        }
        float cm = em;
        #pragma unroll
        for (int off = 1; off < 64; off <<= 1) cm = fmaxf(cm, __shfl_xor(cm, off, 64));
        float nm = fmaxf(m, cm);
        float scale = __expf(m - nm);
        ssum *= scale; ax *= scale; ay *= scale; az *= scale; aw *= scale;
        m = nm;
        float wv = (k < s1) ? __expf(em - nm) : 0.f;
        float ws = wv;
        #pragma unroll
        for (int off = 1; off < 64; off <<= 1) ws += __shfl_xor(ws, off, 64);
        ssum += ws;

        int cnt = s1 - base; if (cnt > 64) cnt = 64;
        for (int j = 0; j < cnt; j += 4) {
            int jj = j + g;
            float wj = __shfl(wv, jj, 64);
            int   pj = __shfl(p,  jj, 64);
            if (jj < cnt) {
                int sdj = pj & 0x7FFFFFFF;
                const ushort* __restrict__ row = (pj < 0) ? zr : z;
                ushort4 v = *(const ushort4*)&row[(size_t)sdj * OUT_DIM + l * 4];
                ax = fmaf(wj, bf2f(v.x), ax);
                ay = fmaf(wj, bf2f(v.y), ay);
                az = fmaf(wj, bf2f(v.z), az);
                aw = fmaf(wj, bf2f(v.w), aw);
            }
        }
    }

    ax += __shfl_xor(ax, 16, 64); ax += __shfl_xor(ax, 32, 64);
    ay += __shfl_xor(ay, 16, 64); ay += __shfl_xor(ay, 32, 64);
    az += __shfl_xor(az, 16, 64); az += __shfl_xor(az, 32, 64);
    aw += __shfl_xor(aw, 16, 64); aw += __shfl_xor(aw, 32, 64);

    float inv = 1.f / fmaxf(ssum, 1e-9f);
    if (g == 0)
        *(float4*)&out[(size_t)node * OUT_DIM + l * 4] =
            make_float4(ax * inv, ay * inv, az * inv, aw * inv);
}

extern "C" void kernel_launch(void* const* d_in, const int* in_sizes, int n_in,
                              void* d_out, int out_size, void* d_ws, size_t ws_size,
                              hipStream_t stream) {
    const float*  h   = (const float*) d_in[0];
    const float*  Wf  = (const float*) d_in[1];
    const float*  Wfr = (const float*) d_in[2];
    const float*  Wa  = (const float*) d_in[3];
    const float2* dir = (const float2*)d_in[4];
    const int*    src = (const int*)   d_in[5];
    const int*    dst = (const int*)   d_in[6];
    float* out = (float*)d_out;

    // ws (4B words): zb zrb | a4 | counts scanw bbase btot start flag | tmp csr
    ushort*   zb     = (ushort*)d_ws;
    ushort*   zrb    = zb + (size_t)N_NODES * OUT_DIM;
    float4*   a4     = (float4*)(zrb + (size_t)N_NODES * OUT_DIM);
    int*      counts = (int*)(a4 + N_NODES);
    int*      scanw  = counts + 38656;
    int*      bbase  = scanw + 38656;
    int*      btot   = bbase + 256;
    int*      start  = btot + 256;
    int*      flag   = start + 50016;
    int2*     tmp    = (int2*)(flag + 64);
    int*      csr    = (int*)(tmp + E_EDGES);

    const int GB = (N_NODES + 63) / 64;

    probe_kernel   <<<1, 64, 0, stream>>>(flag);
    node_gemm_mfma <<<GB, 256, 0, stream>>>(h, Wf, Wfr, flag, zb, zrb);
    verify_kernel  <<<32, 256, 0, stream>>>(h, Wf, Wfr, zb, zrb, flag);
    node_gemm_valu <<<GB, 256, 0, stream>>>(h, Wf, Wfr, flag, zb, zrb);
    a4_kernel      <<<(N_NODES * 16 + 255) / 256, 256, 0, stream>>>(zb, zrb, Wa, a4);

    sort_hist      <<<NBLK, 256, 0, stream>>>(dst, counts);
    sort_scanA     <<<BUCKETS, 256, 0, stream>>>(counts, scanw, btot);
    sort_scanB     <<<1, 256, 0, stream>>>(btot, bbase);
    sort_scatter1  <<<NBLK, 256, 0, stream>>>(src, dst, dir, scanw, bbase, tmp);
    sort_pass2     <<<BUCKETS, 256, 0, stream>>>(bbase, tmp, csr, start);

    node_aggregate <<<(N_NODES * 64 + 255) / 256, 256, 0, stream>>>(start, csr, a4, zb, zrb, out);
}

// Round 9
// 100.716 us; speedup vs baseline: 2.2601x; 1.0483x over previous
//
#include <hip/hip_runtime.h>

#define N_NODES 50000
#define E_EDGES 800000
#define IN_DIM  128
#define OUT_DIM 64
#define NEG_SLOPE 0.01f
#define LDAP 136                            // padded bf16 row stride

#define BUCKETS 196                         // ceil(N/256): bucket = dst>>8
#define NBLK    196                         // sort blocks
#define CHUNK   4096                        // edges per sort block
#define P2CAP   6144

typedef __attribute__((ext_vector_type(8))) short bf16x8;
typedef __attribute__((ext_vector_type(4))) float f32x4;

__device__ __forceinline__ ushort f2bf(float x) {
    unsigned u = __float_as_uint(x);
    return (ushort)((u + 0x7FFFu + ((u >> 16) & 1u)) >> 16);
}
__device__ __forceinline__ float bf2f(ushort u) {
    return __uint_as_float(((unsigned)u) << 16);
}

// ============ MFMA gemm with inline per-wave layout probe ============
// Each wave probes the 16x16x32 C/D mapping itself (1 extra MFMA), picks
// the epilogue. If neither matches, stores nothing -> verify -> VALU repair.
__global__ __launch_bounds__(256) void node_gemm_mfma(
    const float* __restrict__ h, const float* __restrict__ Wf,
    const float* __restrict__ Wfr,
    ushort* __restrict__ z, ushort* __restrict__ zr)
{
    __shared__ ushort hs [64 * LDAP];
    __shared__ ushort wfs[64 * LDAP];
    __shared__ ushort wrs[64 * LDAP];

    const int t = threadIdx.x;
    const int nb0 = blockIdx.x * 64;
    const int lane = t & 63;
    const int lr   = lane & 15;
    const int lq   = lane >> 4;

    // ---- inline probe (proven r4/r6/r7 values: exact in bf16/fp32) ----
    int flagv;
    {
        bf16x8 af = {0,0,0,0,0,0,0,0};
        bf16x8 bf = {0,0,0,0,0,0,0,0};
        if (lane < 16) {
            af[0] = (short)f2bf((float)(1 + lane));
            bf[0] = (short)f2bf((float)((1 + lane) * (1 + lane)));
        }
        f32x4 pacc = {0.f, 0.f, 0.f, 0.f};
        pacc = __builtin_amdgcn_mfma_f32_16x16x32_bf16(af, bf, pacc, 0, 0, 0);
        bool ok0 = true, ok1 = true;
        #pragma unroll
        for (int r = 0; r < 4; ++r) {
            float e0 = (float)((1 + lq * 4 + r) * (1 + lr) * (1 + lr));
            float e1 = (float)((1 + lr) * (1 + lq * 4 + r) * (1 + lq * 4 + r));
            ok0 = ok0 && (pacc[r] == e0);
            ok1 = ok1 && (pacc[r] == e1);
        }
        flagv = __all(ok0 ? 1 : 0) ? 0 : (__all(ok1 ? 1 : 0) ? 1 : 4);
    }

    #pragma unroll
    for (int i = 0; i < 8; ++i) {
        int elem = i * 1024 + t * 4;
        int row = elem >> 7, col = elem & 127;
        int hn = nb0 + row; if (hn >= N_NODES) hn = N_NODES - 1;
        float4 hv = *(const float4*)&h  [(size_t)hn  * IN_DIM + col];
        float4 fv = *(const float4*)&Wf [(size_t)row * IN_DIM + col];
        float4 rv = *(const float4*)&Wfr[(size_t)row * IN_DIM + col];
        ushort4 hu = { f2bf(hv.x), f2bf(hv.y), f2bf(hv.z), f2bf(hv.w) };
        ushort4 fu = { f2bf(fv.x), f2bf(fv.y), f2bf(fv.z), f2bf(fv.w) };
        ushort4 ru = { f2bf(rv.x), f2bf(rv.y), f2bf(rv.z), f2bf(rv.w) };
        *(ushort4*)&hs [row * LDAP + col] = hu;
        *(ushort4*)&wfs[row * LDAP + col] = fu;
        *(ushort4*)&wrs[row * LDAP + col] = ru;
    }
    __syncthreads();

    const int w = t >> 6;

    f32x4 accf[4], accr[4];
    #pragma unroll
    for (int cb = 0; cb < 4; ++cb) {
        accf[cb] = (f32x4){0.f, 0.f, 0.f, 0.f};
        accr[cb] = (f32x4){0.f, 0.f, 0.f, 0.f};
    }

    #pragma unroll
    for (int kc = 0; kc < 4; ++kc) {
        const int koff = kc * 32 + lq * 8;
        bf16x8 af = *(bf16x8*)&hs[(w * 16 + lr) * LDAP + koff];
        #pragma unroll
        for (int cb = 0; cb < 4; ++cb) {
            bf16x8 bfr = *(bf16x8*)&wfs[(cb * 16 + lr) * LDAP + koff];
            bf16x8 brr = *(bf16x8*)&wrs[(cb * 16 + lr) * LDAP + koff];
            accf[cb] = __builtin_amdgcn_mfma_f32_16x16x32_bf16(af, bfr, accf[cb], 0, 0, 0);
            accr[cb] = __builtin_amdgcn_mfma_f32_16x16x32_bf16(af, brr, accr[cb], 0, 0, 0);
        }
    }

    if (flagv >= 2) return;   // unknown layout: leave z poisoned, valu will repair

    #pragma unroll
    for (int reg = 0; reg < 4; ++reg) {
        const int aIdx = (flagv == 0) ? (lq * 4 + reg) : lr;
        const int bIdx = (flagv == 0) ? lr : (lq * 4 + reg);
        const int node = nb0 + w * 16 + aIdx;
        if (node < N_NODES) {
            #pragma unroll
            for (int cb = 0; cb < 4; ++cb) {
                z [(size_t)node * OUT_DIM + cb * 16 + bIdx] = f2bf(accf[cb][reg]);
                zr[(size_t)node * OUT_DIM + cb * 16 + bIdx] = f2bf(accr[cb][reg]);
            }
        }
    }
}

// ============ verify 8192 sampled z/zr vs fp32 dots ============
// Block-reduces mismatches; plain-stores count to flag[blockIdx] (no pre-zero).
__global__ __launch_bounds__(256) void verify_kernel(
    const float* __restrict__ h, const float* __restrict__ Wf,
    const float* __restrict__ Wfr, const ushort* __restrict__ z,
    const ushort* __restrict__ zr, int* __restrict__ flag)
{
    __shared__ int cnt;
    if (threadIdx.x == 0) cnt = 0;
    __syncthreads();

    int i = blockIdx.x * 256 + threadIdx.x;
    unsigned u = (unsigned)i * 2654435761u;
    int n = (int)(u % (unsigned)N_NODES);
    int o = (int)((u >> 17) & 63);
    const ushort* zz = (i & 1) ? zr : z;
    const float*  W  = (i & 1) ? Wfr : Wf;
    float s = 0.f;
    #pragma unroll 4
    for (int k = 0; k < IN_DIM; k += 4) {
        float4 hv = *(const float4*)&h[(size_t)n * IN_DIM + k];
        float4 wv = *(const float4*)&W[(size_t)o * IN_DIM + k];
        s = fmaf(hv.x, wv.x, s); s = fmaf(hv.y, wv.y, s);
        s = fmaf(hv.z, wv.z, s); s = fmaf(hv.w, wv.w, s);
    }
    float zv = bf2f(zz[(size_t)n * OUT_DIM + o]);
    if (fabsf(s - zv) > 0.125f + 0.02f * fabsf(s)) atomicAdd(&cnt, 1);
    __syncthreads();
    if (threadIdx.x == 0) flag[blockIdx.x] = cnt;
}

// ============ VALU fallback gemm (proven; runs only if verify flagged) ============
__global__ __launch_bounds__(256) void node_gemm_valu(
    const float* __restrict__ h, const float* __restrict__ Wf,
    const float* __restrict__ Wfr, const int* __restrict__ flag,
    ushort* __restrict__ z, ushort* __restrict__ zr)
{
    bool bad = false;
    #pragma unroll
    for (int i = 0; i < 32; ++i) bad = bad || (flag[i] != 0);
    if (!bad) return;

    __shared__ float hs [64][33];
    __shared__ float wfs[64][33];
    __shared__ float wrs[64][33];

    const int tid = threadIdx.x;
    const int og = tid & 15;
    const int ng = tid >> 4;
    const int nb0 = blockIdx.x * 64;

    float accf[4][4] = {{0.f}};
    float accr[4][4] = {{0.f}};

    for (int kb = 0; kb < IN_DIM; kb += 32) {
        __syncthreads();
        const int j = tid & 7;
        const int r0 = tid >> 3;
        for (int rr = r0; rr < 64; rr += 32) {
            int hn = nb0 + rr; if (hn >= N_NODES) hn = N_NODES - 1;
            float4 hv = *(const float4*)&h  [(size_t)hn * IN_DIM + kb + j*4];
            float4 fv = *(const float4*)&Wf [(size_t)rr * IN_DIM + kb + j*4];
            float4 rv = *(const float4*)&Wfr[(size_t)rr * IN_DIM + kb + j*4];
            hs [rr][j*4+0] = hv.x; hs [rr][j*4+1] = hv.y; hs [rr][j*4+2] = hv.z; hs [rr][j*4+3] = hv.w;
            wfs[rr][j*4+0] = fv.x; wfs[rr][j*4+1] = fv.y; wfs[rr][j*4+2] = fv.z; wfs[rr][j*4+3] = fv.w;
            wrs[rr][j*4+0] = rv.x; wrs[rr][j*4+1] = rv.y; wrs[rr][j*4+2] = rv.z; wrs[rr][j*4+3] = rv.w;
        }
        __syncthreads();

        #pragma unroll 8
        for (int k = 0; k < 32; ++k) {
            float hv[4], wfv[4], wrv[4];
            #pragma unroll
            for (int i = 0; i < 4; ++i) hv[i] = hs[ng*4+i][k];
            #pragma unroll
            for (int jj = 0; jj < 4; ++jj) { wfv[jj] = wfs[og*4+jj][k]; wrv[jj] = wrs[og*4+jj][k]; }
            #pragma unroll
            for (int i = 0; i < 4; ++i)
                #pragma unroll
                for (int jj = 0; jj < 4; ++jj) {
                    accf[i][jj] = fmaf(hv[i], wfv[jj], accf[i][jj]);
                    accr[i][jj] = fmaf(hv[i], wrv[jj], accr[i][jj]);
                }
        }
    }

    #pragma unroll
    for (int i = 0; i < 4; ++i) {
        const int n = nb0 + ng*4 + i;
        if (n < N_NODES) {
            #pragma unroll
            for (int jj = 0; jj < 4; ++jj) {
                z [(size_t)n*OUT_DIM + og*4 + jj] = f2bf(accf[i][jj]);
                zr[(size_t)n*OUT_DIM + og*4 + jj] = f2bf(accr[i][jj]);
            }
        }
    }
}

// ============ a4 from global z/zr (layout-independent, proven) ============
__global__ __launch_bounds__(256) void a4_kernel(
    const ushort* __restrict__ z, const ushort* __restrict__ zr,
    const float* __restrict__ Wa, float4* __restrict__ a4)
{
    int gid = blockIdx.x * 256 + threadIdx.x;
    int node = gid >> 4;
    int lr = threadIdx.x & 15;
    if (node >= N_NODES) return;
    ushort4 zv = *(const ushort4*)&z [(size_t)node * OUT_DIM + lr * 4];
    ushort4 rv = *(const ushort4*)&zr[(size_t)node * OUT_DIM + lr * 4];
    float4 ws4 = *(const float4*)&Wa[lr * 4];
    float4 wd4 = *(const float4*)&Wa[64 + lr * 4];
    float pSf = bf2f(zv.x)*ws4.x + bf2f(zv.y)*ws4.y + bf2f(zv.z)*ws4.z + bf2f(zv.w)*ws4.w;
    float pDf = bf2f(zv.x)*wd4.x + bf2f(zv.y)*wd4.y + bf2f(zv.z)*wd4.z + bf2f(zv.w)*wd4.w;
    float pSr = bf2f(rv.x)*ws4.x + bf2f(rv.y)*ws4.y + bf2f(rv.z)*ws4.z + bf2f(rv.w)*ws4.w;
    float pDr = bf2f(rv.x)*wd4.x + bf2f(rv.y)*wd4.y + bf2f(rv.z)*wd4.z + bf2f(rv.w)*wd4.w;
    #pragma unroll
    for (int mm = 1; mm < 16; mm <<= 1) {
        pSf += __shfl_xor(pSf, mm, 64);
        pDf += __shfl_xor(pDf, mm, 64);
        pSr += __shfl_xor(pSr, mm, 64);
        pDr += __shfl_xor(pDr, mm, 64);
    }
    if (lr == 0) a4[node] = make_float4(pSf, pDf, pSr, pDr);
}

// ============ sort chain (frozen; validated r6+r7) ============
__global__ __launch_bounds__(256) void sort_hist(
    const int* __restrict__ dst, int* __restrict__ counts)
{
    __shared__ int bh[BUCKETS];
    const int b = blockIdx.x;
    for (int i = threadIdx.x; i < BUCKETS; i += 256) bh[i] = 0;
    __syncthreads();
    const int base = b * CHUNK;
    const int end = (base + CHUNK < E_EDGES) ? base + CHUNK : E_EDGES;
    for (int i = base + threadIdx.x; i < end; i += 256)
        atomicAdd(&bh[dst[i] >> 8], 1);
    __syncthreads();
    for (int i = threadIdx.x; i < BUCKETS; i += 256)
        counts[i * NBLK + b] = bh[i];
}

__global__ __launch_bounds__(256) void sort_scanA(
    const int* __restrict__ counts, int* __restrict__ scanw, int* __restrict__ btot)
{
    __shared__ int tmp[256];
    const int j = blockIdx.x;
    const int t = threadIdx.x;
    int v = (t < NBLK) ? counts[j * NBLK + t] : 0;
    tmp[t] = v; __syncthreads();
    #pragma unroll
    for (int off = 1; off < 256; off <<= 1) {
        int u = (t >= off) ? tmp[t - off] : 0;
        __syncthreads();
        tmp[t] += u;
        __syncthreads();
    }
    if (t < NBLK) scanw[j * NBLK + t] = tmp[t] - v;
    if (t == 255) btot[j] = tmp[t];
}

__global__ __launch_bounds__(256) void sort_scanB(
    const int* __restrict__ btot, int* __restrict__ bbase)
{
    __shared__ int tmp[256];
    const int t = threadIdx.x;
    int v = (t < BUCKETS) ? btot[t] : 0;
    tmp[t] = v; __syncthreads();
    #pragma unroll
    for (int off = 1; off < 256; off <<= 1) {
        int u = (t >= off) ? tmp[t - off] : 0;
        __syncthreads();
        tmp[t] += u;
        __syncthreads();
    }
    if (t < BUCKETS) bbase[t] = tmp[t] - v;
    if (t == 255) bbase[BUCKETS] = tmp[t];
}

__global__ __launch_bounds__(256) void sort_scatter1(
    const int* __restrict__ src, const int* __restrict__ dst,
    const float2* __restrict__ dir, const int* __restrict__ scanw,
    const int* __restrict__ bbase, int2* __restrict__ tmpbuf)
{
    __shared__ int2 recs[CHUNK];
    __shared__ int bh[BUCKETS];
    __shared__ int sc[256];
    __shared__ int cur[BUCKETS];

    const int b = blockIdx.x;
    const int t = threadIdx.x;
    const int base = b * CHUNK;
    const int end = (base + CHUNK < E_EDGES) ? base + CHUNK : E_EDGES;
    const int cnt = end - base;

    for (int i = t; i < BUCKETS; i += 256) bh[i] = 0;
    __syncthreads();

    for (int i = t; i < cnt; i += 256) {
        int e = base + i;
        int d = dst[e];
        float2 dd = dir[e];
        int pay = src[e] | ((dd.y != 0.f) ? 0x80000000 : 0);
        recs[i] = make_int2(pay, d);
        atomicAdd(&bh[d >> 8], 1);
    }
    __syncthreads();

    sc[t] = (t < BUCKETS) ? bh[t] : 0;
    __syncthreads();
    for (int off = 1; off < 256; off <<= 1) {
        int v = (t >= off) ? sc[t - off] : 0;
        __syncthreads();
        sc[t] += v;
        __syncthreads();
    }
    if (t < BUCKETS) cur[t] = (t > 0) ? sc[t - 1] : 0;
    __syncthreads();

    for (int i = t; i < cnt; i += 256) {
        int2 r = recs[i];
        int bkt = r.y >> 8;
        int loc = atomicAdd(&cur[bkt], 1);
        int lbase = (bkt > 0) ? sc[bkt - 1] : 0;
        tmpbuf[scanw[bkt * NBLK + b] + bbase[bkt] + (loc - lbase)] = r;
    }
}

__global__ __launch_bounds__(256) void sort_pass2(
    const int* __restrict__ bbase, const int2* __restrict__ tmpbuf,
    int* __restrict__ csr, int* __restrict__ start)
{
    __shared__ int nh[256];
    __shared__ int nex[256];
    __shared__ int ncur[256];
    __shared__ int2 recs[P2CAP];

    const int j = blockIdx.x;
    const int t = threadIdx.x;
    const int gbeg = bbase[j];
    const int gend = bbase[j + 1];
    const int cnt = gend - gbeg;
    const bool fits = (cnt <= P2CAP);

    nh[t] = 0;
    __syncthreads();

    for (int i = t; i < cnt; i += 256) {
        int2 r = tmpbuf[gbeg + i];
        if (fits) recs[i] = r;
        atomicAdd(&nh[r.y & 255], 1);
    }
    __syncthreads();

    nex[t] = nh[t];
    __syncthreads();
    for (int off = 1; off < 256; off <<= 1) {
        int v = (t >= off) ? nex[t - off] : 0;
        __syncthreads();
        nex[t] += v;
        __syncthreads();
    }
    int excl = (t > 0) ? nex[t - 1] : 0;
    ncur[t] = excl;
    const int node = j * 256 + t;
    if (node < N_NODES) start[node] = gbeg + excl;
    if (j == BUCKETS - 1 && t == 0) start[N_NODES] = E_EDGES;
    __syncthreads();

    for (int i = t; i < cnt; i += 256) {
        int2 r = fits ? recs[i] : tmpbuf[gbeg + i];
        int lid = r.y & 255;
        int loc = atomicAdd(&ncur[lid], 1);
        csr[gbeg + loc] = r.x;
    }
}

// ============ fused softmax+aggregate: no-max softmax (fp32-safe) ============
__global__ __launch_bounds__(256) void node_aggregate(
    const int* __restrict__ start, const int* __restrict__ csr,
    const float4* __restrict__ a4, const ushort* __restrict__ z,
    const ushort* __restrict__ zr, float* __restrict__ out)
{
    int gid = blockIdx.x * 256 + threadIdx.x;
    int node = gid >> 6;
    int lane = threadIdx.x & 63;
    int l = lane & 15;      // channel quad: cols l*4..l*4+3
    int g = lane >> 4;      // edge slot 0..3
    if (node >= N_NODES) return;

    const int s0 = start[node];
    const int s1 = start[node + 1];
    const float4 an = a4[node];

    float ssum = 0.f;
    float ax = 0.f, ay = 0.f, az = 0.f, aw = 0.f;

    for (int base = s0; base < s1; base += 64) {
        int k = base + lane;
        int p = 0;
        float wv = 0.f;
        if (k < s1) {
            p = csr[k];
            int sd = p & 0x7FFFFFFF;
            float4 a = a4[sd];
            float tl = (p < 0) ? (a.z + an.w) : (a.x + an.y);
            tl = (tl > 0.f) ? tl : NEG_SLOPE * tl;
            wv = __expf(tl);                 // |logit| <~ 20 -> fp32-safe
        }
        float ws = wv;
        #pragma unroll
        for (int off = 1; off < 64; off <<= 1) ws += __shfl_xor(ws, off, 64);
        ssum += ws;

        int cnt = s1 - base; if (cnt > 64) cnt = 64;
        for (int j = 0; j < cnt; j += 4) {
            int jj = j + g;
            float wj = __shfl(wv, jj, 64);
            int   pj = __shfl(p,  jj, 64);
            if (jj < cnt) {
                int sdj = pj & 0x7FFFFFFF;
                const ushort* __restrict__ row = (pj < 0) ? zr : z;
                ushort4 v = *(const ushort4*)&row[(size_t)sdj * OUT_DIM + l * 4];
                ax = fmaf(wj, bf2f(v.x), ax);
                ay = fmaf(wj, bf2f(v.y), ay);
                az = fmaf(wj, bf2f(v.z), az);
                aw = fmaf(wj, bf2f(v.w), aw);
            }
        }
    }

    ax += __shfl_xor(ax, 16, 64); ax += __shfl_xor(ax, 32, 64);
    ay += __shfl_xor(ay, 16, 64); ay += __shfl_xor(ay, 32, 64);
    az += __shfl_xor(az, 16, 64); az += __shfl_xor(az, 32, 64);
    aw += __shfl_xor(aw, 16, 64); aw += __shfl_xor(aw, 32, 64);

    float inv = 1.f / fmaxf(ssum, 1e-9f);
    if (g == 0)
        *(float4*)&out[(size_t)node * OUT_DIM + l * 4] =
            make_float4(ax * inv, ay * inv, az * inv, aw * inv);
}

extern "C" void kernel_launch(void* const* d_in, const int* in_sizes, int n_in,
                              void* d_out, int out_size, void* d_ws, size_t ws_size,
                              hipStream_t stream) {
    const float*  h   = (const float*) d_in[0];
    const float*  Wf  = (const float*) d_in[1];
    const float*  Wfr = (const float*) d_in[2];
    const float*  Wa  = (const float*) d_in[3];
    const float2* dir = (const float2*)d_in[4];
    const int*    src = (const int*)   d_in[5];
    const int*    dst = (const int*)   d_in[6];
    float* out = (float*)d_out;

    // ws (4B words): zb zrb | a4 | counts scanw bbase btot start flag | tmp csr
    ushort*   zb     = (ushort*)d_ws;
    ushort*   zrb    = zb + (size_t)N_NODES * OUT_DIM;
    float4*   a4     = (float4*)(zrb + (size_t)N_NODES * OUT_DIM);
    int*      counts = (int*)(a4 + N_NODES);
    int*      scanw  = counts + 38656;
    int*      bbase  = scanw + 38656;
    int*      btot   = bbase + 256;
    int*      start  = btot + 256;
    int*      flag   = start + 50016;
    int2*     tmp    = (int2*)(flag + 64);
    int*      csr    = (int*)(tmp + E_EDGES);

    const int GB = (N_NODES + 63) / 64;

    node_gemm_mfma <<<GB, 256, 0, stream>>>(h, Wf, Wfr, zb, zrb);
    verify_kernel  <<<32, 256, 0, stream>>>(h, Wf, Wfr, zb, zrb, flag);
    node_gemm_valu <<<GB, 256, 0, stream>>>(h, Wf, Wfr, flag, zb, zrb);
    a4_kernel      <<<(N_NODES * 16 + 255) / 256, 256, 0, stream>>>(zb, zrb, Wa, a4);

    sort_hist      <<<NBLK, 256, 0, stream>>>(dst, counts);
    sort_scanA     <<<BUCKETS, 256, 0, stream>>>(counts, scanw, btot);
    sort_scanB     <<<1, 256, 0, stream>>>(btot, bbase);
    sort_scatter1  <<<NBLK, 256, 0, stream>>>(src, dst, dir, scanw, bbase, tmp);
    sort_pass2     <<<BUCKETS, 256, 0, stream>>>(bbase, tmp, csr, start);

    node_aggregate <<<(N_NODES * 64 + 255) / 256, 256, 0, stream>>>(start, csr, a4, zb, zrb, out);
}

// Round 10
// 81.991 us; speedup vs baseline: 2.7762x; 1.2284x over previous
//
#include <hip/hip_runtime.h>

#define N_NODES 50000
#define E_EDGES 800000
#define IN_DIM  128
#define OUT_DIM 64
#define NEG_SLOPE 0.01f
#define LDAP 136                            // padded bf16 row stride

#define BUCKETS 196                         // ceil(N/256): bucket = dst>>8
#define NBLK    196                         // sort blocks
#define CHUNK   4096                        // edges per sort block
#define P2CAP   6144
#define GB      ((N_NODES + 63) / 64)       // 782 gemm blocks
#define A4B     ((N_NODES * 16 + 255) / 256)// 3125 a4 blocks

typedef __attribute__((ext_vector_type(8))) short bf16x8;
typedef __attribute__((ext_vector_type(4))) float f32x4;

__device__ __forceinline__ ushort f2bf(float x) {
    unsigned u = __float_as_uint(x);
    return (ushort)((u + 0x7FFFu + ((u >> 16) & 1u)) >> 16);
}
__device__ __forceinline__ float bf2f(ushort u) {
    return __uint_as_float(((unsigned)u) << 16);
}

// ============================================================
// k1: blocks [0,GB) = MFMA gemm (inline probe + inline VALU fallback);
//     blocks [GB, GB+NBLK) = sort_hist.
// ============================================================
__global__ __launch_bounds__(256) void k1_gemm_hist(
    const float* __restrict__ h, const float* __restrict__ Wf,
    const float* __restrict__ Wfr, const int* __restrict__ dst,
    ushort* __restrict__ z, ushort* __restrict__ zr, int* __restrict__ counts)
{
    __shared__ ushort smem[3 * 64 * LDAP];   // ~51 KB (gemm) / reused by hist
    const int t = threadIdx.x;

    if (blockIdx.x >= GB) {
        // ---- sort_hist (frozen r6+ body) ----
        int* bh = (int*)smem;
        const int b = blockIdx.x - GB;
        for (int i = t; i < BUCKETS; i += 256) bh[i] = 0;
        __syncthreads();
        const int base = b * CHUNK;
        const int end = (base + CHUNK < E_EDGES) ? base + CHUNK : E_EDGES;
        for (int i = base + t; i < end; i += 256)
            atomicAdd(&bh[dst[i] >> 8], 1);
        __syncthreads();
        for (int i = t; i < BUCKETS; i += 256)
            counts[i * NBLK + b] = bh[i];
        return;
    }

    // ---- MFMA gemm (r9 body, flat smem) ----
    ushort* hs  = smem;
    ushort* wfs = smem + 64 * LDAP;
    ushort* wrs = smem + 2 * 64 * LDAP;

    const int nb0 = blockIdx.x * 64;
    const int lane = t & 63;
    const int lr   = lane & 15;
    const int lq   = lane >> 4;

    // inline probe: C/D mapping (exact bf16/fp32 values, proven r4-r9)
    int flagv;
    {
        bf16x8 af = {0,0,0,0,0,0,0,0};
        bf16x8 bf = {0,0,0,0,0,0,0,0};
        if (lane < 16) {
            af[0] = (short)f2bf((float)(1 + lane));
            bf[0] = (short)f2bf((float)((1 + lane) * (1 + lane)));
        }
        f32x4 pacc = {0.f, 0.f, 0.f, 0.f};
        pacc = __builtin_amdgcn_mfma_f32_16x16x32_bf16(af, bf, pacc, 0, 0, 0);
        bool ok0 = true, ok1 = true;
        #pragma unroll
        for (int r = 0; r < 4; ++r) {
            float e0 = (float)((1 + lq * 4 + r) * (1 + lr) * (1 + lr));
            float e1 = (float)((1 + lr) * (1 + lq * 4 + r) * (1 + lq * 4 + r));
            ok0 = ok0 && (pacc[r] == e0);
            ok1 = ok1 && (pacc[r] == e1);
        }
        flagv = __all(ok0 ? 1 : 0) ? 0 : (__all(ok1 ? 1 : 0) ? 1 : 4);
    }

    #pragma unroll
    for (int i = 0; i < 8; ++i) {
        int elem = i * 1024 + t * 4;
        int row = elem >> 7, col = elem & 127;
        int hn = nb0 + row; if (hn >= N_NODES) hn = N_NODES - 1;
        float4 hv = *(const float4*)&h  [(size_t)hn  * IN_DIM + col];
        float4 fv = *(const float4*)&Wf [(size_t)row * IN_DIM + col];
        float4 rv = *(const float4*)&Wfr[(size_t)row * IN_DIM + col];
        ushort4 hu = { f2bf(hv.x), f2bf(hv.y), f2bf(hv.z), f2bf(hv.w) };
        ushort4 fu = { f2bf(fv.x), f2bf(fv.y), f2bf(fv.z), f2bf(fv.w) };
        ushort4 ru = { f2bf(rv.x), f2bf(rv.y), f2bf(rv.z), f2bf(rv.w) };
        *(ushort4*)&hs [row * LDAP + col] = hu;
        *(ushort4*)&wfs[row * LDAP + col] = fu;
        *(ushort4*)&wrs[row * LDAP + col] = ru;
    }
    __syncthreads();

    if (flagv >= 2) {
        // ---- inline VALU fallback from staged bf16 LDS (self-healing) ----
        const int og = t & 15;
        const int ng = t >> 4;
        #pragma unroll
        for (int i = 0; i < 4; ++i) {
            const int nrow = ng * 4 + i;
            const int node = nb0 + nrow;
            if (node >= N_NODES) continue;
            float acf[4] = {0.f, 0.f, 0.f, 0.f};
            float acr[4] = {0.f, 0.f, 0.f, 0.f};
            for (int k = 0; k < IN_DIM; ++k) {
                float hv = bf2f(hs[nrow * LDAP + k]);
                #pragma unroll
                for (int jj = 0; jj < 4; ++jj) {
                    acf[jj] = fmaf(hv, bf2f(wfs[(og * 4 + jj) * LDAP + k]), acf[jj]);
                    acr[jj] = fmaf(hv, bf2f(wrs[(og * 4 + jj) * LDAP + k]), acr[jj]);
                }
            }
            #pragma unroll
            for (int jj = 0; jj < 4; ++jj) {
                z [(size_t)node * OUT_DIM + og * 4 + jj] = f2bf(acf[jj]);
                zr[(size_t)node * OUT_DIM + og * 4 + jj] = f2bf(acr[jj]);
            }
        }
        return;
    }

    const int w = t >> 6;

    f32x4 accf[4], accr[4];
    #pragma unroll
    for (int cb = 0; cb < 4; ++cb) {
        accf[cb] = (f32x4){0.f, 0.f, 0.f, 0.f};
        accr[cb] = (f32x4){0.f, 0.f, 0.f, 0.f};
    }

    #pragma unroll
    for (int kc = 0; kc < 4; ++kc) {
        const int koff = kc * 32 + lq * 8;
        bf16x8 af = *(bf16x8*)&hs[(w * 16 + lr) * LDAP + koff];
        #pragma unroll
        for (int cb = 0; cb < 4; ++cb) {
            bf16x8 bfr = *(bf16x8*)&wfs[(cb * 16 + lr) * LDAP + koff];
            bf16x8 brr = *(bf16x8*)&wrs[(cb * 16 + lr) * LDAP + koff];
            accf[cb] = __builtin_amdgcn_mfma_f32_16x16x32_bf16(af, bfr, accf[cb], 0, 0, 0);
            accr[cb] = __builtin_amdgcn_mfma_f32_16x16x32_bf16(af, brr, accr[cb], 0, 0, 0);
        }
    }

    #pragma unroll
    for (int reg = 0; reg < 4; ++reg) {
        const int aIdx = (flagv == 0) ? (lq * 4 + reg) : lr;
        const int bIdx = (flagv == 0) ? lr : (lq * 4 + reg);
        const int node = nb0 + w * 16 + aIdx;
        if (node < N_NODES) {
            #pragma unroll
            for (int cb = 0; cb < 4; ++cb) {
                z [(size_t)node * OUT_DIM + cb * 16 + bIdx] = f2bf(accf[cb][reg]);
                zr[(size_t)node * OUT_DIM + cb * 16 + bIdx] = f2bf(accr[cb][reg]);
            }
        }
    }
}

// ============================================================
// k2: blocks [0,A4B) = a4; blocks [A4B, A4B+BUCKETS) = sort_scanA.
// ============================================================
__global__ __launch_bounds__(256) void k2_a4_scanA(
    const ushort* __restrict__ z, const ushort* __restrict__ zr,
    const float* __restrict__ Wa, float4* __restrict__ a4,
    const int* __restrict__ counts, int* __restrict__ scanw,
    int* __restrict__ btot)
{
    __shared__ int tmp[256];
    const int t = threadIdx.x;

    if (blockIdx.x >= A4B) {
        // ---- sort_scanA (frozen r7+ body) ----
        const int j = blockIdx.x - A4B;
        int v = (t < NBLK) ? counts[j * NBLK + t] : 0;
        tmp[t] = v; __syncthreads();
        #pragma unroll
        for (int off = 1; off < 256; off <<= 1) {
            int u = (t >= off) ? tmp[t - off] : 0;
            __syncthreads();
            tmp[t] += u;
            __syncthreads();
        }
        if (t < NBLK) scanw[j * NBLK + t] = tmp[t] - v;
        if (t == 255) btot[j] = tmp[t];
        return;
    }

    // ---- a4 (frozen r4+ body) ----
    int gid = blockIdx.x * 256 + t;
    int node = gid >> 4;
    int lr = t & 15;
    if (node >= N_NODES) return;
    ushort4 zv = *(const ushort4*)&z [(size_t)node * OUT_DIM + lr * 4];
    ushort4 rv = *(const ushort4*)&zr[(size_t)node * OUT_DIM + lr * 4];
    float4 ws4 = *(const float4*)&Wa[lr * 4];
    float4 wd4 = *(const float4*)&Wa[64 + lr * 4];
    float pSf = bf2f(zv.x)*ws4.x + bf2f(zv.y)*ws4.y + bf2f(zv.z)*ws4.z + bf2f(zv.w)*ws4.w;
    float pDf = bf2f(zv.x)*wd4.x + bf2f(zv.y)*wd4.y + bf2f(zv.z)*wd4.z + bf2f(zv.w)*wd4.w;
    float pSr = bf2f(rv.x)*ws4.x + bf2f(rv.y)*ws4.y + bf2f(rv.z)*ws4.z + bf2f(rv.w)*ws4.w;
    float pDr = bf2f(rv.x)*wd4.x + bf2f(rv.y)*wd4.y + bf2f(rv.z)*wd4.z + bf2f(rv.w)*wd4.w;
    #pragma unroll
    for (int mm = 1; mm < 16; mm <<= 1) {
        pSf += __shfl_xor(pSf, mm, 64);
        pDf += __shfl_xor(pDf, mm, 64);
        pSr += __shfl_xor(pSr, mm, 64);
        pDr += __shfl_xor(pDr, mm, 64);
    }
    if (lr == 0) a4[node] = make_float4(pSf, pDf, pSr, pDr);
}

// ============================================================
// k3: scatter with LOCAL bucket-base scan (replaces sort_scanB launch)
// ============================================================
__global__ __launch_bounds__(256) void k3_scatter(
    const int* __restrict__ src, const int* __restrict__ dst,
    const float2* __restrict__ dir, const int* __restrict__ scanw,
    const int* __restrict__ btot, int2* __restrict__ tmpbuf)
{
    __shared__ int2 recs[CHUNK];
    __shared__ int bh[BUCKETS];
    __shared__ int sc[256];
    __shared__ int cur[BUCKETS];
    __shared__ int exb[256];     // local exclusive bucket bases

    const int b = blockIdx.x;
    const int t = threadIdx.x;

    // local scan of btot -> exb (exclusive)
    {
        int v = (t < BUCKETS) ? btot[t] : 0;
        exb[t] = v; __syncthreads();
        #pragma unroll
        for (int off = 1; off < 256; off <<= 1) {
            int u = (t >= off) ? exb[t - off] : 0;
            __syncthreads();
            exb[t] += u;
            __syncthreads();
        }
        int ex = exb[t] - v;
        __syncthreads();
        exb[t] = ex;
        // no sync needed yet; next phase has its own syncs before exb reads
    }

    const int base = b * CHUNK;
    const int end = (base + CHUNK < E_EDGES) ? base + CHUNK : E_EDGES;
    const int cnt = end - base;

    for (int i = t; i < BUCKETS; i += 256) bh[i] = 0;
    __syncthreads();

    for (int i = t; i < cnt; i += 256) {
        int e = base + i;
        int d = dst[e];
        float2 dd = dir[e];
        int pay = src[e] | ((dd.y != 0.f) ? 0x80000000 : 0);
        recs[i] = make_int2(pay, d);
        atomicAdd(&bh[d >> 8], 1);
    }
    __syncthreads();

    sc[t] = (t < BUCKETS) ? bh[t] : 0;
    __syncthreads();
    #pragma unroll
    for (int off = 1; off < 256; off <<= 1) {
        int v = (t >= off) ? sc[t - off] : 0;
        __syncthreads();
        sc[t] += v;
        __syncthreads();
    }
    if (t < BUCKETS) cur[t] = (t > 0) ? sc[t - 1] : 0;
    __syncthreads();

    for (int i = t; i < cnt; i += 256) {
        int2 r = recs[i];
        int bkt = r.y >> 8;
        int loc = atomicAdd(&cur[bkt], 1);
        int lbase = (bkt > 0) ? sc[bkt - 1] : 0;
        tmpbuf[scanw[bkt * NBLK + b] + exb[bkt] + (loc - lbase)] = r;
    }
}

// ============================================================
// k4: pass2 with LOCAL bucket-base scan; emits csr + start[]
// ============================================================
__global__ __launch_bounds__(256) void k4_pass2(
    const int* __restrict__ btot, const int2* __restrict__ tmpbuf,
    int* __restrict__ csr, int* __restrict__ start)
{
    __shared__ int nh[256];
    __shared__ int nex[256];
    __shared__ int ncur[256];
    __shared__ int stmp[256];
    __shared__ int2 recs[P2CAP];

    const int j = blockIdx.x;
    const int t = threadIdx.x;

    // local scan of btot -> exclusive base for bucket j
    int v = (t < BUCKETS) ? btot[t] : 0;
    stmp[t] = v; __syncthreads();
    #pragma unroll
    for (int off = 1; off < 256; off <<= 1) {
        int u = (t >= off) ? stmp[t - off] : 0;
        __syncthreads();
        stmp[t] += u;
        __syncthreads();
    }
    const int gbeg = stmp[j] - btot[j];     // exclusive base of bucket j
    const int cnt  = btot[j];
    const bool fits = (cnt <= P2CAP);

    nh[t] = 0;
    __syncthreads();

    for (int i = t; i < cnt; i += 256) {
        int2 r = tmpbuf[gbeg + i];
        if (fits) recs[i] = r;
        atomicAdd(&nh[r.y & 255], 1);
    }
    __syncthreads();

    nex[t] = nh[t];
    __syncthreads();
    #pragma unroll
    for (int off = 1; off < 256; off <<= 1) {
        int u = (t >= off) ? nex[t - off] : 0;
        __syncthreads();
        nex[t] += u;
        __syncthreads();
    }
    int excl = (t > 0) ? nex[t - 1] : 0;
    ncur[t] = excl;
    const int node = j * 256 + t;
    if (node < N_NODES) start[node] = gbeg + excl;
    if (j == BUCKETS - 1 && t == 0) start[N_NODES] = E_EDGES;
    __syncthreads();

    for (int i = t; i < cnt; i += 256) {
        int2 r = fits ? recs[i] : tmpbuf[gbeg + i];
        int lid = r.y & 255;
        int loc = atomicAdd(&ncur[lid], 1);
        csr[gbeg + loc] = r.x;
    }
}

// ============================================================
// k5: fused softmax+aggregate (frozen r9 body: no-max softmax)
// ============================================================
__global__ __launch_bounds__(256) void k5_aggregate(
    const int* __restrict__ start, const int* __restrict__ csr,
    const float4* __restrict__ a4, const ushort* __restrict__ z,
    const ushort* __restrict__ zr, float* __restrict__ out)
{
    int gid = blockIdx.x * 256 + threadIdx.x;
    int node = gid >> 6;
    int lane = threadIdx.x & 63;
    int l = lane & 15;
    int g = lane >> 4;
    if (node >= N_NODES) return;

    const int s0 = start[node];
    const int s1 = start[node + 1];
    const float4 an = a4[node];

    float ssum = 0.f;
    float ax = 0.f, ay = 0.f, az = 0.f, aw = 0.f;

    for (int base = s0; base < s1; base += 64) {
        int k = base + lane;
        int p = 0;
        float wv = 0.f;
        if (k < s1) {
            p = csr[k];
            int sd = p & 0x7FFFFFFF;
            float4 a = a4[sd];
            float tl = (p < 0) ? (a.z + an.w) : (a.x + an.y);
            tl = (tl > 0.f) ? tl : NEG_SLOPE * tl;
            wv = __expf(tl);
        }
        float ws = wv;
        #pragma unroll
        for (int off = 1; off < 64; off <<= 1) ws += __shfl_xor(ws, off, 64);
        ssum += ws;

        int cnt = s1 - base; if (cnt > 64) cnt = 64;
        for (int j = 0; j < cnt; j += 4) {
            int jj = j + g;
            float wj = __shfl(wv, jj, 64);
            int   pj = __shfl(p,  jj, 64);
            if (jj < cnt) {
                int sdj = pj & 0x7FFFFFFF;
                const ushort* __restrict__ row = (pj < 0) ? zr : z;
                ushort4 v = *(const ushort4*)&row[(size_t)sdj * OUT_DIM + l * 4];
                ax = fmaf(wj, bf2f(v.x), ax);
                ay = fmaf(wj, bf2f(v.y), ay);
                az = fmaf(wj, bf2f(v.z), az);
                aw = fmaf(wj, bf2f(v.w), aw);
            }
        }
    }

    ax += __shfl_xor(ax, 16, 64); ax += __shfl_xor(ax, 32, 64);
    ay += __shfl_xor(ay, 16, 64); ay += __shfl_xor(ay, 32, 64);
    az += __shfl_xor(az, 16, 64); az += __shfl_xor(az, 32, 64);
    aw += __shfl_xor(aw, 16, 64); aw += __shfl_xor(aw, 32, 64);

    float inv = 1.f / fmaxf(ssum, 1e-9f);
    if (g == 0)
        *(float4*)&out[(size_t)node * OUT_DIM + l * 4] =
            make_float4(ax * inv, ay * inv, az * inv, aw * inv);
}

extern "C" void kernel_launch(void* const* d_in, const int* in_sizes, int n_in,
                              void* d_out, int out_size, void* d_ws, size_t ws_size,
                              hipStream_t stream) {
    const float*  h   = (const float*) d_in[0];
    const float*  Wf  = (const float*) d_in[1];
    const float*  Wfr = (const float*) d_in[2];
    const float*  Wa  = (const float*) d_in[3];
    const float2* dir = (const float2*)d_in[4];
    const int*    src = (const int*)   d_in[5];
    const int*    dst = (const int*)   d_in[6];
    float* out = (float*)d_out;

    // ws (4B words): zb zrb | a4 | counts scanw btot start | tmp csr
    ushort*   zb     = (ushort*)d_ws;
    ushort*   zrb    = zb + (size_t)N_NODES * OUT_DIM;
    float4*   a4     = (float4*)(zrb + (size_t)N_NODES * OUT_DIM);
    int*      counts = (int*)(a4 + N_NODES);
    int*      scanw  = counts + 38656;
    int*      btot   = scanw + 38656;
    int*      start  = btot + 256;
    int2*     tmp    = (int2*)(start + 50016);
    int*      csr    = (int*)(tmp + E_EDGES);

    k1_gemm_hist <<<GB + NBLK, 256, 0, stream>>>(h, Wf, Wfr, dst, zb, zrb, counts);
    k2_a4_scanA  <<<A4B + BUCKETS, 256, 0, stream>>>(zb, zrb, Wa, a4, counts, scanw, btot);
    k3_scatter   <<<NBLK, 256, 0, stream>>>(src, dst, dir, scanw, btot, tmp);
    k4_pass2     <<<BUCKETS, 256, 0, stream>>>(btot, tmp, csr, start);
    k5_aggregate <<<(N_NODES * 64 + 255) / 256, 256, 0, stream>>>(start, csr, a4, zb, zrb, out);
}